// Round 2
// baseline (14952.879 us; speedup 1.0000x reference)
//
#include <hip/hip_runtime.h>

#define NBLK 8
#define BROWS 131072
#define HDIM 512
#define EPSV 1e-5f

// 32 rows per workgroup: hbuf = 32*512*2 = 32 KiB -> 4 wgs/CU (16 waves/CU).
#define WROWS 32

typedef __bf16 bf16x8 __attribute__((ext_vector_type(8)));
typedef float f32x4 __attribute__((ext_vector_type(4)));

__device__ __forceinline__ int swz(int row, int k) {
  return row * HDIM + (k ^ ((row & 7) << 3));
}

__device__ __forceinline__ float act_tanh_f(float x) {
  float e = __expf(2.f * fminf(x, 15.f));
  return (e - 1.f) / (e + 1.f);
}

template <int ACT>
__device__ __forceinline__ float apply_act(float v) {
  if (ACT == 1) return act_tanh_f(v);
  return fmaxf(v, 0.f);
}

// ---------------- hidden layer: h (LDS 32x512 bf16) -> h in place -----------
// 4 waves x 128-col N-slices; explicit 2x-unrolled k-loop with B double-buffer.
template <int ACT>
__device__ __forceinline__ void dense_h(const __bf16* __restrict__ Wt,
                                        const float* __restrict__ bias,
                                        __bf16* hb, int wave, int c, int quad) {
  const int nb = wave * 128;
  f32x4 acc[2][8];
#pragma unroll
  for (int mt = 0; mt < 2; ++mt)
#pragma unroll
    for (int nt = 0; nt < 8; ++nt) acc[mt][nt] = (f32x4){0.f, 0.f, 0.f, 0.f};

  const int msk = (c & 7) << 3;
  const __bf16* wp = Wt + (size_t)(nb + c) * HDIM + quad * 8;

  bf16x8 b0[8], b1[8];
#pragma unroll
  for (int nt = 0; nt < 8; ++nt)
    b0[nt] = *(const bf16x8*)(wp + (size_t)nt * 16 * HDIM);

#pragma unroll
  for (int kt = 0; kt < HDIM; kt += 64) {
    // prefetch k-step kt+32 while computing kt
#pragma unroll
    for (int nt = 0; nt < 8; ++nt)
      b1[nt] = *(const bf16x8*)(wp + (size_t)nt * 16 * HDIM + kt + 32);
    {
      const int kq = kt + quad * 8;
      bf16x8 a0 = *(const bf16x8*)&hb[(0 * 16 + c) * HDIM + (kq ^ msk)];
      bf16x8 a1 = *(const bf16x8*)&hb[(1 * 16 + c) * HDIM + (kq ^ msk)];
#pragma unroll
      for (int nt = 0; nt < 8; ++nt) {
        acc[0][nt] = __builtin_amdgcn_mfma_f32_16x16x32_bf16(a0, b0[nt], acc[0][nt], 0, 0, 0);
        acc[1][nt] = __builtin_amdgcn_mfma_f32_16x16x32_bf16(a1, b0[nt], acc[1][nt], 0, 0, 0);
      }
    }
    if (kt + 64 < HDIM) {
#pragma unroll
      for (int nt = 0; nt < 8; ++nt)
        b0[nt] = *(const bf16x8*)(wp + (size_t)nt * 16 * HDIM + kt + 64);
    }
    {
      const int kq = kt + 32 + quad * 8;
      bf16x8 a0 = *(const bf16x8*)&hb[(0 * 16 + c) * HDIM + (kq ^ msk)];
      bf16x8 a1 = *(const bf16x8*)&hb[(1 * 16 + c) * HDIM + (kq ^ msk)];
#pragma unroll
      for (int nt = 0; nt < 8; ++nt) {
        acc[0][nt] = __builtin_amdgcn_mfma_f32_16x16x32_bf16(a0, b1[nt], acc[0][nt], 0, 0, 0);
        acc[1][nt] = __builtin_amdgcn_mfma_f32_16x16x32_bf16(a1, b1[nt], acc[1][nt], 0, 0, 0);
      }
    }
  }
  __syncthreads();  // all reads of hb done -> safe to overwrite in place
#pragma unroll
  for (int nt = 0; nt < 8; ++nt) {
    const float bs = bias[nb + nt * 16 + c];
#pragma unroll
    for (int mt = 0; mt < 2; ++mt)
#pragma unroll
      for (int i = 0; i < 4; ++i) {
        const int row = mt * 16 + quad * 4 + i;
        float v = apply_act<ACT>(acc[mt][nt][i] + bs);
        hb[swz(row, nb + nt * 16 + c)] = (__bf16)v;
      }
  }
  __syncthreads();
}

// layer 0: ys (registers) -> h. K=32 (one MFMA k-step).
template <int ACT>
__device__ __forceinline__ void dense_l0(const __bf16* __restrict__ Wt0,
                                         const float* __restrict__ bias,
                                         const bf16x8 aYs[2], __bf16* hb,
                                         int wave, int c, int quad) {
  const int nb = wave * 128;
  f32x4 acc[2][8];
#pragma unroll
  for (int mt = 0; mt < 2; ++mt)
#pragma unroll
    for (int nt = 0; nt < 8; ++nt) acc[mt][nt] = (f32x4){0.f, 0.f, 0.f, 0.f};
  bf16x8 b[8];
#pragma unroll
  for (int nt = 0; nt < 8; ++nt)
    b[nt] = *(const bf16x8*)&Wt0[(size_t)(nb + nt * 16 + c) * 32 + quad * 8];
#pragma unroll
  for (int mt = 0; mt < 2; ++mt)
#pragma unroll
    for (int nt = 0; nt < 8; ++nt)
      acc[mt][nt] = __builtin_amdgcn_mfma_f32_16x16x32_bf16(aYs[mt], b[nt], acc[mt][nt], 0, 0, 0);
  __syncthreads();  // prior readers of hb done before overwrite
#pragma unroll
  for (int nt = 0; nt < 8; ++nt) {
    const float bs = bias[nb + nt * 16 + c];
#pragma unroll
    for (int mt = 0; mt < 2; ++mt)
#pragma unroll
      for (int i = 0; i < 4; ++i) {
        const int row = mt * 16 + quad * 4 + i;
        float v = apply_act<ACT>(acc[mt][nt][i] + bs);
        hb[swz(row, nb + nt * 16 + c)] = (__bf16)v;
      }
  }
  __syncthreads();
}

// output head: h -> 32 cols, no act. Wave (rt = wave&1, nth = wave>>1)
// computes rows rt*16+.., cols nth*16+c -> one f32x4.
__device__ __forceinline__ void head(const __bf16* __restrict__ Wot,
                                     const float* __restrict__ bias,
                                     const __bf16* hb, int rt, int nth, int c,
                                     int quad, f32x4& out) {
  const int msk = (c & 7) << 3;
  const __bf16* wp = Wot + (size_t)(nth * 16 + c) * HDIM + quad * 8;
  f32x4 acc = (f32x4){0.f, 0.f, 0.f, 0.f};
  bf16x8 b0 = *(const bf16x8*)wp, b1;
#pragma unroll
  for (int kt = 0; kt < HDIM; kt += 64) {
    b1 = *(const bf16x8*)(wp + kt + 32);
    {
      bf16x8 a = *(const bf16x8*)&hb[(rt * 16 + c) * HDIM + ((kt + quad * 8) ^ msk)];
      acc = __builtin_amdgcn_mfma_f32_16x16x32_bf16(a, b0, acc, 0, 0, 0);
    }
    if (kt + 64 < HDIM) b0 = *(const bf16x8*)(wp + kt + 64);
    {
      bf16x8 a = *(const bf16x8*)&hb[(rt * 16 + c) * HDIM + ((kt + 32 + quad * 8) ^ msk)];
      acc = __builtin_amdgcn_mfma_f32_16x16x32_bf16(a, b1, acc, 0, 0, 0);
    }
  }
  const float bs = bias[nth * 16 + c];
#pragma unroll
  for (int i = 0; i < 4; ++i) out[i] = acc[i] + bs;
}

// ---------------- coupling-block kernel -------------------------------------

template <bool FIRST>
__global__ __launch_bounds__(256, 4) void couple_kernel(
    const float* __restrict__ src, float* __restrict__ zbuf,
    float* __restrict__ ld,
    const __bf16* __restrict__ sW0t, const float* __restrict__ sb0,
    const __bf16* __restrict__ sWht, const float* __restrict__ sbh,
    const __bf16* __restrict__ sWot, const float* __restrict__ sbo,
    const __bf16* __restrict__ tW0t, const float* __restrict__ tb0,
    const __bf16* __restrict__ tWht, const float* __restrict__ tbh,
    const __bf16* __restrict__ tWot, const float* __restrict__ tbo,
    const float* __restrict__ prevP,  // A[64], C[64] of previous batchnorm
    float* __restrict__ stats_out,    // sum[64], sumsq[64] accumulators
    int o)                            // ys column offset (0 or 32)
{
  __shared__ __bf16 hbuf[WROWS * HDIM];  // 32 KiB

  const int tid = threadIdx.x;
  const int wave = tid >> 6;
  const int lane = tid & 63;
  const int c = lane & 15;
  const int quad = lane >> 4;
  const size_t row0 = (size_t)blockIdx.x * WROWS;

  // ---- load ys tile into A-fragment registers (bf16), applying prev BN ----
  float pA[8], pC[8];
  {
    const int cb = o + quad * 8;
#pragma unroll
    for (int j = 0; j < 8; ++j) {
      pA[j] = FIRST ? 1.f : prevP[cb + j];
      pC[j] = FIRST ? 0.f : prevP[64 + cb + j];
    }
  }
  bf16x8 aYs[2];
#pragma unroll
  for (int mt = 0; mt < 2; ++mt) {
    const size_t r = row0 + mt * 16 + c;
    const float* p = &src[r * 64 + o + quad * 8];
    float4 v0 = *(const float4*)p;
    float4 v1 = *(const float4*)(p + 4);
    float f[8] = {v0.x, v0.y, v0.z, v0.w, v1.x, v1.y, v1.z, v1.w};
#pragma unroll
    for (int j = 0; j < 8; ++j) aYs[mt][j] = (__bf16)(pA[j] * f[j] + pC[j]);
  }

  const int rt = wave & 1;
  const int nth = wave >> 1;
  f32x4 sfr, tfr;

  // ---- s-net (tanh) ----
  dense_l0<1>(sW0t, sb0, aYs, hbuf, wave, c, quad);
  for (int l = 0; l < 3; ++l)
    dense_h<1>(sWht + (size_t)l * HDIM * HDIM, sbh + l * HDIM, hbuf, wave, c, quad);
  head(sWot, sbo, hbuf, rt, nth, c, quad, sfr);

  // ---- t-net (relu) ----
  dense_l0<2>(tW0t, tb0, aYs, hbuf, wave, c, quad);
  for (int l = 0; l < 3; ++l)
    dense_h<2>(tWht + (size_t)l * HDIM * HDIM, tbh + l * HDIM, hbuf, wave, c, quad);
  head(tWot, tbo, hbuf, rt, nth, c, quad, tfr);

  // ---- combine ----
  __syncthreads();  // hbuf reads done; reuse as scratch
  float* colsum = (float*)hbuf;        // [64]
  float* colsq = colsum + 64;          // [64]
  float* ldp = colsum + 128;           // [32]
  if (tid < 160) colsum[tid] = 0.f;
  __syncthreads();

  const int oc = o ^ 32;
  const int rw = (int)row0 + rt * 16;

  {  // zc half: col = oc + nth*16 + c
    const int col = oc + nth * 16 + c;
    const float A_ = FIRST ? 1.f : prevP[col];
    const float C_ = FIRST ? 0.f : prevP[64 + col];
    float csum = 0.f, csq = 0.f;
#pragma unroll
    for (int i = 0; i < 4; ++i) {
      const int r = rw + quad * 4 + i;
      const size_t idx = (size_t)r * 64 + col;
      float yc = A_ * src[idx] + C_;
      const float s = sfr[i];
      const float zc = yc * __expf(s) + tfr[i];
      zbuf[idx] = zc;
      csum += zc; csq += zc * zc;
      // per-row logdet partial over this wave's 16 cols
      float v = s;
      v += __shfl_xor(v, 1); v += __shfl_xor(v, 2);
      v += __shfl_xor(v, 4); v += __shfl_xor(v, 8);
      if (c == 0) atomicAdd(&ldp[rt * 16 + quad * 4 + i], v);
    }
    csum += __shfl_xor(csum, 16); csum += __shfl_xor(csum, 32);
    csq  += __shfl_xor(csq, 16);  csq  += __shfl_xor(csq, 32);
    if (quad == 0) { atomicAdd(&colsum[col], csum); atomicAdd(&colsq[col], csq); }
  }
  {  // ys half (normalized pass-through): col = o + nth*16 + c
    const int col = o + nth * 16 + c;
    const float A_ = FIRST ? 1.f : prevP[col];
    const float C_ = FIRST ? 0.f : prevP[64 + col];
    float csum = 0.f, csq = 0.f;
#pragma unroll
    for (int i = 0; i < 4; ++i) {
      const int r = rw + quad * 4 + i;
      const size_t idx = (size_t)r * 64 + col;
      float v = A_ * src[idx] + C_;
      zbuf[idx] = v;
      csum += v; csq += v * v;
    }
    csum += __shfl_xor(csum, 16); csum += __shfl_xor(csum, 32);
    csq  += __shfl_xor(csq, 16);  csq  += __shfl_xor(csq, 32);
    if (quad == 0) { atomicAdd(&colsum[col], csum); atomicAdd(&colsq[col], csq); }
  }

  __syncthreads();
  if (tid < 64) {
    atomicAdd(&stats_out[tid], colsum[tid]);
    atomicAdd(&stats_out[64 + tid], colsq[tid]);
  } else if (tid < 96) {
    const int r = (int)row0 + tid - 64;
    const float v = ldp[tid - 64];
    if (FIRST) ld[r] = v; else ld[r] += v;
  }
}

// ---------------- small kernels ---------------------------------------------

__global__ void stats_kernel(const float* __restrict__ raw,
                             const float* __restrict__ lg,
                             const float* __restrict__ beta,
                             float* __restrict__ param,
                             float* __restrict__ ld_scalar) {
  const int t = threadIdx.x;  // 64 threads
  const float S = raw[t], SS = raw[64 + t];
  const float mean = S / (float)BROWS;
  const float var = (SS - S * mean) / (float)(BROWS - 1);
  const float inv = rsqrtf(var + EPSV);
  const float g = __expf(lg[t]);
  const float A = g * inv;
  param[t] = A;
  param[64 + t] = beta[t] - mean * A;
  float contrib = lg[t] - 0.5f * __logf(var + EPSV);
  contrib += __shfl_xor(contrib, 1);  contrib += __shfl_xor(contrib, 2);
  contrib += __shfl_xor(contrib, 4);  contrib += __shfl_xor(contrib, 8);
  contrib += __shfl_xor(contrib, 16); contrib += __shfl_xor(contrib, 32);
  if (t == 0) atomicAdd(ld_scalar, contrib);
}

__global__ void final_kernel(float* __restrict__ out,
                             const float* __restrict__ param7,
                             const float* __restrict__ ld_scalar) {
  const size_t gid = (size_t)blockIdx.x * 256 + threadIdx.x;
  const size_t total = (size_t)BROWS * 64;
  const int col = gid & 63;
  const float z = out[gid];
  out[gid] = param7[col] * z + param7[64 + col];
  if (gid < BROWS) out[total + gid] += ld_scalar[0];
}

// W[k][n] (fp32) -> Wt[n][k] (bf16)
__global__ void transpose_bf16(const float* __restrict__ src,
                               __bf16* __restrict__ dst, int K, int N) {
  __shared__ float tile[32][33];
  const int bz = blockIdx.z;
  const float* s = src + (size_t)bz * K * N;
  __bf16* dd = dst + (size_t)bz * K * N;
  const int tx = threadIdx.x, ty = threadIdx.y;  // 32 x 8
#pragma unroll
  for (int i = 0; i < 4; ++i) {
    const int k = blockIdx.y * 32 + ty + i * 8;
    const int n = blockIdx.x * 32 + tx;
    tile[ty + i * 8][tx] = s[(size_t)k * N + n];
  }
  __syncthreads();
#pragma unroll
  for (int i = 0; i < 4; ++i) {
    const int n = blockIdx.x * 32 + ty + i * 8;
    const int k = blockIdx.y * 32 + tx;
    dd[(size_t)n * K + k] = (__bf16)tile[tx][ty + i * 8];
  }
}

// ---------------- launcher --------------------------------------------------

extern "C" void kernel_launch(void* const* d_in, const int* in_sizes, int n_in,
                              void* d_out, int out_size, void* d_ws, size_t ws_size,
                              hipStream_t stream) {
  const float* y_in = (const float*)d_in[0];
  const float* sW0 = (const float*)d_in[1];
  const float* sb0 = (const float*)d_in[2];
  const float* sWh = (const float*)d_in[3];
  const float* sbh = (const float*)d_in[4];
  const float* sWo = (const float*)d_in[5];
  const float* sbo = (const float*)d_in[6];
  const float* tW0 = (const float*)d_in[7];
  const float* tb0 = (const float*)d_in[8];
  const float* tWh = (const float*)d_in[9];
  const float* tbh = (const float*)d_in[10];
  const float* tWo = (const float*)d_in[11];
  const float* tbo = (const float*)d_in[12];
  const float* bn_lg = (const float*)d_in[13];
  const float* bn_bt = (const float*)d_in[14];

  char* p = (char*)d_ws;
  __bf16* sW0t = (__bf16*)p; p += (size_t)NBLK * 32 * 512 * 2;
  __bf16* sWht = (__bf16*)p; p += (size_t)NBLK * 3 * 512 * 512 * 2;
  __bf16* sWot = (__bf16*)p; p += (size_t)NBLK * 512 * 32 * 2;
  __bf16* tW0t = (__bf16*)p; p += (size_t)NBLK * 32 * 512 * 2;
  __bf16* tWht = (__bf16*)p; p += (size_t)NBLK * 3 * 512 * 512 * 2;
  __bf16* tWot = (__bf16*)p; p += (size_t)NBLK * 512 * 32 * 2;
  float* stats_raw = (float*)p; p += NBLK * 128 * 4;
  float* ld_scalar = (float*)p; p += 16;
  float* stats_param = (float*)p; p += NBLK * 128 * 4;

  float* out = (float*)d_out;
  float* zbuf = out;                           // z lives in d_out's y region
  float* ld = out + (size_t)BROWS * 64;

  dim3 tb(32, 8, 1);
  transpose_bf16<<<dim3(16, 1, 8),  tb, 0, stream>>>(sW0, sW0t, 32, 512);
  transpose_bf16<<<dim3(16, 16, 24), tb, 0, stream>>>(sWh, sWht, 512, 512);
  transpose_bf16<<<dim3(1, 16, 8),  tb, 0, stream>>>(sWo, sWot, 512, 32);
  transpose_bf16<<<dim3(16, 1, 8),  tb, 0, stream>>>(tW0, tW0t, 32, 512);
  transpose_bf16<<<dim3(16, 16, 24), tb, 0, stream>>>(tWh, tWht, 512, 512);
  transpose_bf16<<<dim3(1, 16, 8),  tb, 0, stream>>>(tWo, tWot, 512, 32);
  hipMemsetAsync(stats_raw, 0, NBLK * 128 * 4 + 16, stream);

  for (int b = 0; b < NBLK; ++b) {
    const int o = (b & 1) ? 32 : 0;
    const __bf16* W0t_ = sW0t + (size_t)b * 16384;
    const __bf16* Wht_ = sWht + (size_t)b * 3 * 512 * 512;
    const __bf16* Wot_ = sWot + (size_t)b * 16384;
    const __bf16* tW0t_ = tW0t + (size_t)b * 16384;
    const __bf16* tWht_ = tWht + (size_t)b * 3 * 512 * 512;
    const __bf16* tWot_ = tWot + (size_t)b * 16384;
    const float* pb0 = sb0 + b * 512;
    const float* pbh = sbh + b * 1536;
    const float* pbo = sbo + b * 32;
    const float* qb0 = tb0 + b * 512;
    const float* qbh = tbh + b * 1536;
    const float* qbo = tbo + b * 32;
    float* praw = stats_raw + b * 128;

    if (b == 0)
      couple_kernel<true><<<BROWS / WROWS, 256, 0, stream>>>(
          y_in, zbuf, ld, W0t_, pb0, Wht_, pbh, Wot_, pbo,
          tW0t_, qb0, tWht_, qbh, tWot_, qbo, nullptr, praw, o);
    else
      couple_kernel<false><<<BROWS / WROWS, 256, 0, stream>>>(
          zbuf, zbuf, ld, W0t_, pb0, Wht_, pbh, Wot_, pbo,
          tW0t_, qb0, tWht_, qbh, tWot_, qbo,
          stats_param + (size_t)(b - 1) * 128, praw, o);

    stats_kernel<<<1, 64, 0, stream>>>(praw, bn_lg + b * 64, bn_bt + b * 64,
                                       stats_param + (size_t)b * 128, ld_scalar);
  }

  final_kernel<<<(BROWS * 64) / 256, 256, 0, stream>>>(
      out, stats_param + 7 * 128, ld_scalar);
}

// Round 3
// 10140.491 us; speedup vs baseline: 1.4746x; 1.4746x over previous
//
#include <hip/hip_runtime.h>

#define NBLK 8
#define BROWS 131072
#define HDIM 512
#define EPSV 1e-5f

// 128 rows per 512-thread workgroup. hbuf 128 KiB + ysb 8 KiB = 136 KiB LDS.
#define WROWS 128

typedef __bf16 bf16x8 __attribute__((ext_vector_type(8)));
typedef float f32x4 __attribute__((ext_vector_type(4)));

// elems per packed net stream: l0 16384 + 3*262144 + head 16384
#define PACK_NET 819200
#define PACK_L0 0
#define PACK_H 16384
#define PACK_HEAD 802816

__device__ __forceinline__ float act_tanh_f(float x) {
  float e = __expf(2.f * fminf(x, 15.f));
  return (e - 1.f) / (e + 1.f);
}

template <int ACT>
__device__ __forceinline__ float apply_act(float v) {
  if (ACT == 1) return act_tanh_f(v);
  return fmaxf(v, 0.f);
}

// ---- hidden layer: h (LDS 128x512 bf16, swizzled) -> h in place ------------
// wave w owns output cols [64w, 64w+64); reads all 128 rows.
template <int ACT>
__device__ __forceinline__ void dense_h(const __bf16* __restrict__ Wp,
                                        const float* __restrict__ bias,
                                        __bf16* hb, int w, int c, int quad,
                                        int lane) {
  f32x4 acc[8][4];
#pragma unroll
  for (int mt = 0; mt < 8; ++mt)
#pragma unroll
    for (int nt = 0; nt < 4; ++nt) acc[mt][nt] = (f32x4){0.f, 0.f, 0.f, 0.f};

  const __bf16* wp = Wp + (size_t)w * 32768 + lane * 8;
  bf16x8 br[3][4];
#pragma unroll
  for (int s = 0; s < 2; ++s)
#pragma unroll
    for (int nt = 0; nt < 4; ++nt)
      br[s][nt] = *(const bf16x8*)(wp + s * 2048 + nt * 512);

  const int msk = (c & 7) << 3;
#pragma unroll
  for (int kt = 0; kt < 16; ++kt) {
    if (kt + 2 < 16) {
#pragma unroll
      for (int nt = 0; nt < 4; ++nt)
        br[(kt + 2) % 3][nt] = *(const bf16x8*)(wp + (kt + 2) * 2048 + nt * 512);
    }
    const int sk = (kt * 32 + quad * 8) ^ msk;
    bf16x8 a[8];
#pragma unroll
    for (int mt = 0; mt < 8; ++mt)
      a[mt] = *(const bf16x8*)&hb[(mt * 16 + c) * HDIM + sk];
#pragma unroll
    for (int mt = 0; mt < 8; ++mt)
#pragma unroll
      for (int nt = 0; nt < 4; ++nt)
        acc[mt][nt] = __builtin_amdgcn_mfma_f32_16x16x32_bf16(a[mt], br[kt % 3][nt], acc[mt][nt], 0, 0, 0);
  }
  __syncthreads();  // all reads of hb done -> safe to overwrite in place
#pragma unroll
  for (int nt = 0; nt < 4; ++nt) {
    const float bs = bias[w * 64 + nt * 16 + c];
    const int col = w * 64 + nt * 16 + c;
#pragma unroll
    for (int mt = 0; mt < 8; ++mt)
#pragma unroll
      for (int i = 0; i < 4; ++i) {
        const int row = mt * 16 + quad * 4 + i;
        float v = apply_act<ACT>(acc[mt][nt][i] + bs);
        hb[row * HDIM + (col ^ ((row & 7) << 3))] = (__bf16)v;
      }
  }
  __syncthreads();
}

// ---- layer 0: ysb (LDS 128x32 bf16) -> h. K=32 -----------------------------
template <int ACT>
__device__ __forceinline__ void dense_l0(const __bf16* __restrict__ Wp,
                                         const float* __restrict__ bias,
                                         const __bf16* ysb, __bf16* hb, int w,
                                         int c, int quad, int lane) {
  f32x4 acc[8][4];
#pragma unroll
  for (int mt = 0; mt < 8; ++mt)
#pragma unroll
    for (int nt = 0; nt < 4; ++nt) acc[mt][nt] = (f32x4){0.f, 0.f, 0.f, 0.f};
  const __bf16* wp = Wp + (size_t)w * 2048 + lane * 8;
  bf16x8 b[4];
#pragma unroll
  for (int nt = 0; nt < 4; ++nt) b[nt] = *(const bf16x8*)(wp + nt * 512);
  const int sk = (quad * 8) ^ ((c & 3) << 3);
  bf16x8 a[8];
#pragma unroll
  for (int mt = 0; mt < 8; ++mt)
    a[mt] = *(const bf16x8*)&ysb[(mt * 16 + c) * 32 + sk];
#pragma unroll
  for (int mt = 0; mt < 8; ++mt)
#pragma unroll
    for (int nt = 0; nt < 4; ++nt)
      acc[mt][nt] = __builtin_amdgcn_mfma_f32_16x16x32_bf16(a[mt], b[nt], acc[mt][nt], 0, 0, 0);
  __syncthreads();  // prior readers of hb (head of other net) done
#pragma unroll
  for (int nt = 0; nt < 4; ++nt) {
    const float bs = bias[w * 64 + nt * 16 + c];
    const int col = w * 64 + nt * 16 + c;
#pragma unroll
    for (int mt = 0; mt < 8; ++mt)
#pragma unroll
      for (int i = 0; i < 4; ++i) {
        const int row = mt * 16 + quad * 4 + i;
        float v = apply_act<ACT>(acc[mt][nt][i] + bs);
        hb[row * HDIM + (col ^ ((row & 7) << 3))] = (__bf16)v;
      }
  }
  __syncthreads();
}

// ---- head: h -> 32 cols for this wave's 16 rows (rows 16w..16w+15) ---------
__device__ __forceinline__ void head(const __bf16* __restrict__ Wp,
                                     const float* __restrict__ bias,
                                     const __bf16* hb, int w, int c, int quad,
                                     int lane, f32x4 out[2]) {
  f32x4 acc[2] = {(f32x4){0.f, 0.f, 0.f, 0.f}, (f32x4){0.f, 0.f, 0.f, 0.f}};
  const __bf16* wp = Wp + lane * 8;
  bf16x8 br[3][2];
#pragma unroll
  for (int s = 0; s < 2; ++s)
#pragma unroll
    for (int nt = 0; nt < 2; ++nt)
      br[s][nt] = *(const bf16x8*)(wp + s * 1024 + nt * 512);
  const int msk = (c & 7) << 3;
#pragma unroll
  for (int kt = 0; kt < 16; ++kt) {
    if (kt + 2 < 16) {
#pragma unroll
      for (int nt = 0; nt < 2; ++nt)
        br[(kt + 2) % 3][nt] = *(const bf16x8*)(wp + (kt + 2) * 1024 + nt * 512);
    }
    const int sk = (kt * 32 + quad * 8) ^ msk;
    bf16x8 a = *(const bf16x8*)&hb[(w * 16 + c) * HDIM + sk];
#pragma unroll
    for (int nt = 0; nt < 2; ++nt)
      acc[nt] = __builtin_amdgcn_mfma_f32_16x16x32_bf16(a, br[kt % 3][nt], acc[nt], 0, 0, 0);
  }
#pragma unroll
  for (int nt = 0; nt < 2; ++nt) {
    const float bs = bias[nt * 16 + c];
#pragma unroll
    for (int i = 0; i < 4; ++i) out[nt][i] = acc[nt][i] + bs;
  }
}

// ---------------- coupling-block kernel -------------------------------------

template <bool FIRST>
__global__ __launch_bounds__(512, 2) void couple_kernel(
    const float* __restrict__ src, float* __restrict__ zbuf,
    float* __restrict__ ld,
    const __bf16* __restrict__ pwS,  // packed s-net weights for this block
    const __bf16* __restrict__ pwT,  // packed t-net weights
    const float* __restrict__ sb0, const float* __restrict__ sbh,
    const float* __restrict__ sbo,
    const float* __restrict__ tb0, const float* __restrict__ tbh,
    const float* __restrict__ tbo,
    const float* __restrict__ prevP,  // A[64], C[64] of previous batchnorm
    float* __restrict__ stats_out,    // sum[64], sumsq[64] accumulators
    int o)                            // ys column offset (0 or 32)
{
  __shared__ __bf16 hbuf[WROWS * HDIM];  // 128 KiB
  __shared__ __bf16 ysb[WROWS * 32];     // 8 KiB

  const int tid = threadIdx.x;
  const int w = tid >> 6;
  const int lane = tid & 63;
  const int c = lane & 15;
  const int quad = lane >> 4;
  const size_t row0 = (size_t)blockIdx.x * WROWS;

  // ---- prologue: normalized ys (bf16) into ysb -----------------------------
  {
    const int row = tid >> 2, grp = tid & 3;
    const float* p = &src[(row0 + row) * 64 + o + grp * 8];
    float4 v0 = *(const float4*)p;
    float4 v1 = *(const float4*)(p + 4);
    float f[8] = {v0.x, v0.y, v0.z, v0.w, v1.x, v1.y, v1.z, v1.w};
    bf16x8 pv;
#pragma unroll
    for (int j = 0; j < 8; ++j) {
      const int col = o + grp * 8 + j;
      const float A_ = FIRST ? 1.f : prevP[col];
      const float C_ = FIRST ? 0.f : prevP[64 + col];
      pv[j] = (__bf16)(A_ * f[j] + C_);
    }
    *(bf16x8*)&ysb[row * 32 + ((grp * 8) ^ ((row & 3) << 3))] = pv;
  }
  __syncthreads();

  f32x4 sfr[2], tfr[2];

  // ---- s-net (tanh) ----
  dense_l0<1>(pwS + PACK_L0, sb0, ysb, hbuf, w, c, quad, lane);
  for (int l = 0; l < 3; ++l)
    dense_h<1>(pwS + PACK_H + (size_t)l * 262144, sbh + l * HDIM, hbuf, w, c, quad, lane);
  head(pwS + PACK_HEAD, sbo, hbuf, w, c, quad, lane, sfr);

  // ---- t-net (relu) ----
  dense_l0<2>(pwT + PACK_L0, tb0, ysb, hbuf, w, c, quad, lane);
  for (int l = 0; l < 3; ++l)
    dense_h<2>(pwT + PACK_H + (size_t)l * 262144, tbh + l * HDIM, hbuf, w, c, quad, lane);
  head(pwT + PACK_HEAD, tbo, hbuf, w, c, quad, lane, tfr);

  // ---- combine ----
  __syncthreads();  // t-head hb reads done; reuse hbuf as scratch
  float* colsum = (float*)hbuf;  // [64]
  float* colsq = colsum + 64;    // [64]
  if (tid < 128) colsum[tid] = 0.f;
  __syncthreads();

  const int oc = o ^ 32;
  const int rw = (int)row0 + w * 16;

#pragma unroll
  for (int nt = 0; nt < 2; ++nt) {  // zc half
    const int col = oc + nt * 16 + c;
    const float A_ = FIRST ? 1.f : prevP[col];
    const float C_ = FIRST ? 0.f : prevP[64 + col];
    float csum = 0.f, csq = 0.f;
#pragma unroll
    for (int i = 0; i < 4; ++i) {
      const int r = rw + quad * 4 + i;
      const size_t idx = (size_t)r * 64 + col;
      float yc = A_ * src[idx] + C_;
      const float s = sfr[nt][i];
      const float zc = yc * __expf(s) + tfr[nt][i];
      zbuf[idx] = zc;
      csum += zc; csq += zc * zc;
    }
    csum += __shfl_xor(csum, 16); csum += __shfl_xor(csum, 32);
    csq  += __shfl_xor(csq, 16);  csq  += __shfl_xor(csq, 32);
    if (quad == 0) { atomicAdd(&colsum[col], csum); atomicAdd(&colsq[col], csq); }
  }

  // per-row logdet: rows of this wave are unique to it
#pragma unroll
  for (int i = 0; i < 4; ++i) {
    float v = sfr[0][i] + sfr[1][i];
    v += __shfl_xor(v, 1); v += __shfl_xor(v, 2);
    v += __shfl_xor(v, 4); v += __shfl_xor(v, 8);
    if (c == 0) {
      const int r = rw + quad * 4 + i;
      if (FIRST) ld[r] = v; else ld[r] += v;
    }
  }

#pragma unroll
  for (int nt = 0; nt < 2; ++nt) {  // ys half (normalized pass-through)
    const int col = o + nt * 16 + c;
    const float A_ = FIRST ? 1.f : prevP[col];
    const float C_ = FIRST ? 0.f : prevP[64 + col];
    float csum = 0.f, csq = 0.f;
#pragma unroll
    for (int i = 0; i < 4; ++i) {
      const int r = rw + quad * 4 + i;
      const size_t idx = (size_t)r * 64 + col;
      float v = A_ * src[idx] + C_;
      zbuf[idx] = v;
      csum += v; csq += v * v;
    }
    csum += __shfl_xor(csum, 16); csum += __shfl_xor(csum, 32);
    csq  += __shfl_xor(csq, 16);  csq  += __shfl_xor(csq, 32);
    if (quad == 0) { atomicAdd(&colsum[col], csum); atomicAdd(&colsq[col], csq); }
  }

  __syncthreads();
  if (tid < 64) {
    atomicAdd(&stats_out[tid], colsum[tid]);
    atomicAdd(&stats_out[64 + tid], colsq[tid]);
  }
}

// ---------------- small kernels ---------------------------------------------

__global__ void stats_kernel(const float* __restrict__ raw,
                             const float* __restrict__ lg,
                             const float* __restrict__ beta,
                             float* __restrict__ param,
                             float* __restrict__ ld_scalar) {
  const int t = threadIdx.x;  // 64 threads
  const float S = raw[t], SS = raw[64 + t];
  const float mean = S / (float)BROWS;
  const float var = (SS - S * mean) / (float)(BROWS - 1);
  const float inv = rsqrtf(var + EPSV);
  const float g = __expf(lg[t]);
  const float A = g * inv;
  param[t] = A;
  param[64 + t] = beta[t] - mean * A;
  float contrib = lg[t] - 0.5f * __logf(var + EPSV);
  contrib += __shfl_xor(contrib, 1);  contrib += __shfl_xor(contrib, 2);
  contrib += __shfl_xor(contrib, 4);  contrib += __shfl_xor(contrib, 8);
  contrib += __shfl_xor(contrib, 16); contrib += __shfl_xor(contrib, 32);
  if (t == 0) atomicAdd(ld_scalar, contrib);
}

__global__ void final_kernel(float* __restrict__ out,
                             const float* __restrict__ param7,
                             const float* __restrict__ ld_scalar) {
  const size_t gid = (size_t)blockIdx.x * 256 + threadIdx.x;
  const size_t total = (size_t)BROWS * 64;
  const int col = gid & 63;
  const float z = out[gid];
  out[gid] = param7[col] * z + param7[64 + col];
  if (gid < BROWS) out[total + gid] += ld_scalar[0];
}

// ---- pack weights into per-wave sequential MFMA-fragment streams -----------
// per net stream (819200 elems): [l0: w][nt][lane][8] | [h l][w][kt][nt][lane][8]
// | [head: kt][nt2][lane][8]
__global__ void pack_weights(const float* __restrict__ sW0,
                             const float* __restrict__ sWh,
                             const float* __restrict__ sWo,
                             const float* __restrict__ tW0,
                             const float* __restrict__ tWh,
                             const float* __restrict__ tWo,
                             __bf16* __restrict__ dst) {
  const int gid = blockIdx.x * 256 + threadIdx.x;  // 1,638,400 threads
  const int gpn = PACK_NET / 8;                    // 102400 groups per net
  const int b = gid / (2 * gpn);
  const int r = gid % (2 * gpn);
  const int net = r / gpn;
  const size_t o = (size_t)(r % gpn) * 8;
  const float* W0 = net ? tW0 : sW0;
  const float* Wh = net ? tWh : sWh;
  const float* Wo = net ? tWo : sWo;
  __bf16* d = dst + ((size_t)b * 2 + net) * PACK_NET + o;
  float v[8];
  if (o < PACK_H) {  // l0: K=32, cols 512
    const int lane = (int)(o >> 3) & 63, nt = (int)(o >> 9) & 3, w = (int)(o >> 11);
    const int cc = lane & 15, q = lane >> 4;
    const int col = w * 64 + nt * 16 + cc;
    const float* s = W0 + (size_t)b * 32 * 512;
#pragma unroll
    for (int j = 0; j < 8; ++j) v[j] = s[(size_t)(q * 8 + j) * 512 + col];
  } else if (o < PACK_HEAD) {  // hidden: K=512, cols 512
    const size_t oo = o - PACK_H;
    const int l = (int)(oo >> 18);
    const int rr = (int)(oo & 262143);
    const int lane = (rr >> 3) & 63, nt = (rr >> 9) & 3, kt = (rr >> 11) & 15,
              w = rr >> 15;
    const int cc = lane & 15, q = lane >> 4;
    const int col = w * 64 + nt * 16 + cc;
    const float* s = Wh + ((size_t)(b * 3 + l)) * 512 * 512;
#pragma unroll
    for (int j = 0; j < 8; ++j) v[j] = s[(size_t)(kt * 32 + q * 8 + j) * 512 + col];
  } else {  // head: K=512, cols 32
    const size_t oo = o - PACK_HEAD;
    const int lane = (int)(oo >> 3) & 63, nt = (int)(oo >> 9) & 1, kt = (int)(oo >> 10);
    const int cc = lane & 15, q = lane >> 4;
    const int col = nt * 16 + cc;
    const float* s = Wo + (size_t)b * 512 * 32;
#pragma unroll
    for (int j = 0; j < 8; ++j) v[j] = s[(size_t)(kt * 32 + q * 8 + j) * 32 + col];
  }
  bf16x8 pv;
#pragma unroll
  for (int j = 0; j < 8; ++j) pv[j] = (__bf16)v[j];
  *(bf16x8*)d = pv;
}

// ---------------- launcher --------------------------------------------------

extern "C" void kernel_launch(void* const* d_in, const int* in_sizes, int n_in,
                              void* d_out, int out_size, void* d_ws, size_t ws_size,
                              hipStream_t stream) {
  const float* y_in = (const float*)d_in[0];
  const float* sW0 = (const float*)d_in[1];
  const float* sb0 = (const float*)d_in[2];
  const float* sWh = (const float*)d_in[3];
  const float* sbh = (const float*)d_in[4];
  const float* sWo = (const float*)d_in[5];
  const float* sbo = (const float*)d_in[6];
  const float* tW0 = (const float*)d_in[7];
  const float* tb0 = (const float*)d_in[8];
  const float* tWh = (const float*)d_in[9];
  const float* tbh = (const float*)d_in[10];
  const float* tWo = (const float*)d_in[11];
  const float* tbo = (const float*)d_in[12];
  const float* bn_lg = (const float*)d_in[13];
  const float* bn_bt = (const float*)d_in[14];

  char* p = (char*)d_ws;
  __bf16* packed = (__bf16*)p; p += (size_t)NBLK * 2 * PACK_NET * 2;
  float* stats_raw = (float*)p; p += NBLK * 128 * 4;
  float* ld_scalar = (float*)p; p += 16;
  float* stats_param = (float*)p; p += NBLK * 128 * 4;

  float* out = (float*)d_out;
  float* zbuf = out;  // z lives in d_out's y region
  float* ld = out + (size_t)BROWS * 64;

  pack_weights<<<(NBLK * 2 * PACK_NET / 8) / 256, 256, 0, stream>>>(
      sW0, sWh, sWo, tW0, tWh, tWo, packed);
  hipMemsetAsync(stats_raw, 0, NBLK * 128 * 4 + 16, stream);

  for (int b = 0; b < NBLK; ++b) {
    const int o = (b & 1) ? 32 : 0;
    const __bf16* pwS = packed + (size_t)b * 2 * PACK_NET;
    const __bf16* pwT = pwS + PACK_NET;
    float* praw = stats_raw + b * 128;

    if (b == 0)
      couple_kernel<true><<<BROWS / WROWS, 512, 0, stream>>>(
          y_in, zbuf, ld, pwS, pwT, sb0 + b * 512, sbh + b * 1536, sbo + b * 32,
          tb0 + b * 512, tbh + b * 1536, tbo + b * 32, nullptr, praw, o);
    else
      couple_kernel<false><<<BROWS / WROWS, 512, 0, stream>>>(
          zbuf, zbuf, ld, pwS, pwT, sb0 + b * 512, sbh + b * 1536, sbo + b * 32,
          tb0 + b * 512, tbh + b * 1536, tbo + b * 32,
          stats_param + (size_t)(b - 1) * 128, praw, o);

    stats_kernel<<<1, 64, 0, stream>>>(praw, bn_lg + b * 64, bn_bt + b * 64,
                                       stats_param + (size_t)b * 128, ld_scalar);
  }

  final_kernel<<<(BROWS * 64) / 256, 256, 0, stream>>>(
      out, stats_param + 7 * 128, ld_scalar);
}

// Round 4
// 7126.868 us; speedup vs baseline: 2.0981x; 1.4229x over previous
//
#include <hip/hip_runtime.h>

#define NBLK 8
#define BROWS 131072
#define HDIM 512
#define EPSV 1e-5f
#define WROWS 128

typedef __bf16 bf16x8 __attribute__((ext_vector_type(8)));
typedef float f32x4 __attribute__((ext_vector_type(4)));

#define PACK_NET 819200
#define PACK_L0 0
#define PACK_H 16384
#define PACK_HEAD 802816

__device__ __forceinline__ float act_tanh_f(float x) {
  float e = __expf(2.f * fminf(x, 15.f));
  return (e - 1.f) / (e + 1.f);
}

template <int ACT>
__device__ __forceinline__ float apply_act(float v) {
  if (ACT == 1) return act_tanh_f(v);
  return fmaxf(v, 0.f);
}

template <int ACT>
__device__ __forceinline__ void dense_h(const __bf16* __restrict__ Wp,
                                        const float* __restrict__ bias,
                                        __bf16* hb, int w, int c, int quad,
                                        int lane) {
  f32x4 acc[8][4];
#pragma unroll
  for (int mt = 0; mt < 8; ++mt)
#pragma unroll
    for (int nt = 0; nt < 4; ++nt) acc[mt][nt] = (f32x4){0.f, 0.f, 0.f, 0.f};

  const __bf16* wp = Wp + (size_t)w * 32768 + lane * 8;
  bf16x8 br[3][4];
#pragma unroll
  for (int s = 0; s < 2; ++s)
#pragma unroll
    for (int nt = 0; nt < 4; ++nt)
      br[s][nt] = *(const bf16x8*)(wp + s * 2048 + nt * 512);

  const int msk = (c & 7) << 3;
#pragma unroll
  for (int kt = 0; kt < 16; ++kt) {
    if (kt + 2 < 16) {
#pragma unroll
      for (int nt = 0; nt < 4; ++nt)
        br[(kt + 2) % 3][nt] = *(const bf16x8*)(wp + (kt + 2) * 2048 + nt * 512);
    }
    const int sk = (kt * 32 + quad * 8) ^ msk;
    bf16x8 a[8];
#pragma unroll
    for (int mt = 0; mt < 8; ++mt)
      a[mt] = *(const bf16x8*)&hb[(mt * 16 + c) * HDIM + sk];
#pragma unroll
    for (int mt = 0; mt < 8; ++mt)
#pragma unroll
      for (int nt = 0; nt < 4; ++nt)
        acc[mt][nt] = __builtin_amdgcn_mfma_f32_16x16x32_bf16(a[mt], br[kt % 3][nt], acc[mt][nt], 0, 0, 0);
  }
  __syncthreads();
#pragma unroll
  for (int nt = 0; nt < 4; ++nt) {
    const float bs = bias[w * 64 + nt * 16 + c];
    const int col = w * 64 + nt * 16 + c;
#pragma unroll
    for (int mt = 0; mt < 8; ++mt)
#pragma unroll
      for (int i = 0; i < 4; ++i) {
        const int row = mt * 16 + quad * 4 + i;
        float v = apply_act<ACT>(acc[mt][nt][i] + bs);
        hb[row * HDIM + (col ^ ((row & 7) << 3))] = (__bf16)v;
      }
  }
  __syncthreads();
}

template <int ACT>
__device__ __forceinline__ void dense_l0(const __bf16* __restrict__ Wp,
                                         const float* __restrict__ bias,
                                         const __bf16* ysb, __bf16* hb, int w,
                                         int c, int quad, int lane) {
  f32x4 acc[8][4];
#pragma unroll
  for (int mt = 0; mt < 8; ++mt)
#pragma unroll
    for (int nt = 0; nt < 4; ++nt) acc[mt][nt] = (f32x4){0.f, 0.f, 0.f, 0.f};
  const __bf16* wp = Wp + (size_t)w * 2048 + lane * 8;
  bf16x8 b[4];
#pragma unroll
  for (int nt = 0; nt < 4; ++nt) b[nt] = *(const bf16x8*)(wp + nt * 512);
  const int sk = (quad * 8) ^ ((c & 3) << 3);
  bf16x8 a[8];
#pragma unroll
  for (int mt = 0; mt < 8; ++mt)
    a[mt] = *(const bf16x8*)&ysb[(mt * 16 + c) * 32 + sk];
#pragma unroll
  for (int mt = 0; mt < 8; ++mt)
#pragma unroll
    for (int nt = 0; nt < 4; ++nt)
      acc[mt][nt] = __builtin_amdgcn_mfma_f32_16x16x32_bf16(a[mt], b[nt], acc[mt][nt], 0, 0, 0);
  __syncthreads();
#pragma unroll
  for (int nt = 0; nt < 4; ++nt) {
    const float bs = bias[w * 64 + nt * 16 + c];
    const int col = w * 64 + nt * 16 + c;
#pragma unroll
    for (int mt = 0; mt < 8; ++mt)
#pragma unroll
      for (int i = 0; i < 4; ++i) {
        const int row = mt * 16 + quad * 4 + i;
        float v = apply_act<ACT>(acc[mt][nt][i] + bs);
        hb[row * HDIM + (col ^ ((row & 7) << 3))] = (__bf16)v;
      }
  }
  __syncthreads();
}

__device__ __forceinline__ void head(const __bf16* __restrict__ Wp,
                                     const float* __restrict__ bias,
                                     const __bf16* hb, int w, int c, int quad,
                                     int lane, f32x4 out[2]) {
  f32x4 acc[2] = {(f32x4){0.f, 0.f, 0.f, 0.f}, (f32x4){0.f, 0.f, 0.f, 0.f}};
  const __bf16* wp = Wp + lane * 8;
  bf16x8 br[3][2];
#pragma unroll
  for (int s = 0; s < 2; ++s)
#pragma unroll
    for (int nt = 0; nt < 2; ++nt)
      br[s][nt] = *(const bf16x8*)(wp + s * 1024 + nt * 512);
  const int msk = (c & 7) << 3;
#pragma unroll
  for (int kt = 0; kt < 16; ++kt) {
    if (kt + 2 < 16) {
#pragma unroll
      for (int nt = 0; nt < 2; ++nt)
        br[(kt + 2) % 3][nt] = *(const bf16x8*)(wp + (kt + 2) * 1024 + nt * 512);
    }
    const int sk = (kt * 32 + quad * 8) ^ msk;
    bf16x8 a = *(const bf16x8*)&hb[(w * 16 + c) * HDIM + sk];
#pragma unroll
    for (int nt = 0; nt < 2; ++nt)
      acc[nt] = __builtin_amdgcn_mfma_f32_16x16x32_bf16(a, br[kt % 3][nt], acc[nt], 0, 0, 0);
  }
#pragma unroll
  for (int nt = 0; nt < 2; ++nt) {
    const float bs = bias[nt * 16 + c];
#pragma unroll
    for (int i = 0; i < 4; ++i) out[nt][i] = acc[nt][i] + bs;
  }
}

__device__ __forceinline__ void stage_in(const __bf16* __restrict__ hg,
                                         __bf16* hb, size_t row0, int w,
                                         int lane) {
#pragma unroll
  for (int i = 0; i < 16; ++i) {
    const int row = w * 16 + i;
    bf16x8 v = *(const bf16x8*)&hg[(row0 + row) * HDIM + lane * 8];
    *(bf16x8*)&hb[row * HDIM + ((lane * 8) ^ ((row & 7) << 3))] = v;
  }
}

__device__ __forceinline__ void copy_out(const __bf16* hb,
                                         __bf16* __restrict__ hg, size_t row0,
                                         int w, int lane) {
#pragma unroll
  for (int i = 0; i < 16; ++i) {
    const int row = w * 16 + i;
    bf16x8 v = *(const bf16x8*)&hb[row * HDIM + ((lane * 8) ^ ((row & 7) << 3))];
    *(bf16x8*)&hg[(row0 + row) * HDIM + lane * 8] = v;
  }
}

template <int ACT, bool FIRST>
__global__ __launch_bounds__(512, 2) void mlp_front(
    const float* __restrict__ src, const __bf16* __restrict__ pw,
    const float* __restrict__ b0, const float* __restrict__ bh,
    const float* __restrict__ prevP, __bf16* __restrict__ hg, int o,
    int row0base) {
  __shared__ __bf16 hbuf[WROWS * HDIM];
  __shared__ __bf16 ysb[WROWS * 32];
  const int tid = threadIdx.x;
  const int w = tid >> 6, lane = tid & 63, c = lane & 15, quad = lane >> 4;
  const size_t row0 = (size_t)row0base + (size_t)blockIdx.x * WROWS;

  {
    const int row = tid >> 2, g = tid & 3;
    const float* p = &src[(row0 + row) * 64 + o + g * 8];
    float4 v0 = *(const float4*)p;
    float4 v1 = *(const float4*)(p + 4);
    float f[8] = {v0.x, v0.y, v0.z, v0.w, v1.x, v1.y, v1.z, v1.w};
    bf16x8 pv;
#pragma unroll
    for (int j = 0; j < 8; ++j) {
      const int col = o + g * 8 + j;
      const float A_ = FIRST ? 1.f : prevP[col];
      const float C_ = FIRST ? 0.f : prevP[64 + col];
      pv[j] = (__bf16)(A_ * f[j] + C_);
    }
    *(bf16x8*)&ysb[row * 32 + ((g * 8) ^ ((row & 3) << 3))] = pv;
  }
  __syncthreads();

  dense_l0<ACT>(pw + PACK_L0, b0, ysb, hbuf, w, c, quad, lane);
  dense_h<ACT>(pw + PACK_H, bh, hbuf, w, c, quad, lane);
  copy_out(hbuf, hg, row0, w, lane);
}

template <int ACT>
__global__ __launch_bounds__(512, 2) void mlp_mid(const __bf16* __restrict__ pw,
                                                  const float* __restrict__ bh,
                                                  __bf16* __restrict__ hg,
                                                  int row0base) {
  __shared__ __bf16 hbuf[WROWS * HDIM];
  const int tid = threadIdx.x;
  const int w = tid >> 6, lane = tid & 63, c = lane & 15, quad = lane >> 4;
  const size_t row0 = (size_t)row0base + (size_t)blockIdx.x * WROWS;
  stage_in(hg, hbuf, row0, w, lane);
  __syncthreads();
  dense_h<ACT>(pw, bh, hbuf, w, c, quad, lane);
  copy_out(hbuf, hg, row0, w, lane);
}

template <int ACT>
__global__ __launch_bounds__(512, 2) void mlp_back(
    const __bf16* __restrict__ pw, const float* __restrict__ bh,
    const __bf16* __restrict__ pwo, const float* __restrict__ bo,
    const __bf16* __restrict__ hg, float* __restrict__ outg, int row0base) {
  __shared__ __bf16 hbuf[WROWS * HDIM];
  const int tid = threadIdx.x;
  const int w = tid >> 6, lane = tid & 63, c = lane & 15, quad = lane >> 4;
  const size_t row0 = (size_t)row0base + (size_t)blockIdx.x * WROWS;
  stage_in(hg, hbuf, row0, w, lane);
  __syncthreads();
  dense_h<ACT>(pw, bh, hbuf, w, c, quad, lane);
  f32x4 fr[2];
  head(pwo, bo, hbuf, w, c, quad, lane, fr);
#pragma unroll
  for (int nt = 0; nt < 2; ++nt)
#pragma unroll
    for (int i = 0; i < 4; ++i)
      outg[(row0 + w * 16 + quad * 4 + i) * 32 + nt * 16 + c] = fr[nt][i];
}

template <bool FIRST>
__global__ __launch_bounds__(256, 4) void combine_kernel(
    const float* __restrict__ src, const float* __restrict__ sout,
    const float* __restrict__ tout, const float* __restrict__ prevP,
    float* __restrict__ zbuf, float* __restrict__ ld,
    float* __restrict__ stats_out, int o, int row0base) {
  __shared__ float cs[128];
  const int tid = threadIdx.x;
  if (tid < 128) cs[tid] = 0.f;
  __syncthreads();
  const int rl = tid >> 2, g = tid & 3, lane = tid & 63;
  const size_t row = (size_t)row0base + (size_t)blockIdx.x * 64 + rl;
  const int oc = o ^ 32;

  float sv[8], tv[8];
  {
    float4 a = *(const float4*)&sout[row * 32 + g * 8];
    float4 b = *(const float4*)&sout[row * 32 + g * 8 + 4];
    sv[0] = a.x; sv[1] = a.y; sv[2] = a.z; sv[3] = a.w;
    sv[4] = b.x; sv[5] = b.y; sv[6] = b.z; sv[7] = b.w;
    float4 e = *(const float4*)&tout[row * 32 + g * 8];
    float4 f = *(const float4*)&tout[row * 32 + g * 8 + 4];
    tv[0] = e.x; tv[1] = e.y; tv[2] = e.z; tv[3] = e.w;
    tv[4] = f.x; tv[5] = f.y; tv[6] = f.z; tv[7] = f.w;
  }

  float zc[8], yn[8];
  {
    const float* p = &src[row * 64 + oc + g * 8];
    float4 y0 = *(const float4*)p;
    float4 y1 = *(const float4*)(p + 4);
    float yv[8] = {y0.x, y0.y, y0.z, y0.w, y1.x, y1.y, y1.z, y1.w};
#pragma unroll
    for (int j = 0; j < 8; ++j) {
      const int col = oc + g * 8 + j;
      const float A_ = FIRST ? 1.f : prevP[col];
      const float C_ = FIRST ? 0.f : prevP[64 + col];
      zc[j] = (A_ * yv[j] + C_) * __expf(sv[j]) + tv[j];
    }
    float4 o0 = {zc[0], zc[1], zc[2], zc[3]};
    float4 o1 = {zc[4], zc[5], zc[6], zc[7]};
    *(float4*)&zbuf[row * 64 + oc + g * 8] = o0;
    *(float4*)&zbuf[row * 64 + oc + g * 8 + 4] = o1;
  }
  {
    const float* p = &src[row * 64 + o + g * 8];
    float4 y0 = *(const float4*)p;
    float4 y1 = *(const float4*)(p + 4);
    float yv[8] = {y0.x, y0.y, y0.z, y0.w, y1.x, y1.y, y1.z, y1.w};
#pragma unroll
    for (int j = 0; j < 8; ++j) {
      const int col = o + g * 8 + j;
      const float A_ = FIRST ? 1.f : prevP[col];
      const float C_ = FIRST ? 0.f : prevP[64 + col];
      yn[j] = A_ * yv[j] + C_;
    }
    float4 o0 = {yn[0], yn[1], yn[2], yn[3]};
    float4 o1 = {yn[4], yn[5], yn[6], yn[7]};
    *(float4*)&zbuf[row * 64 + o + g * 8] = o0;
    *(float4*)&zbuf[row * 64 + o + g * 8 + 4] = o1;
  }

  {
    float v = sv[0] + sv[1] + sv[2] + sv[3] + sv[4] + sv[5] + sv[6] + sv[7];
    v += __shfl_xor(v, 1);
    v += __shfl_xor(v, 2);
    if (g == 0) {
      if (FIRST) ld[row] = v; else ld[row] += v;
    }
  }

#pragma unroll
  for (int j = 0; j < 8; ++j) {
    float v = zc[j], q = zc[j] * zc[j];
#pragma unroll
    for (int m = 4; m < 64; m <<= 1) { v += __shfl_xor(v, m); q += __shfl_xor(q, m); }
    if (lane < 4) {
      const int col = oc + g * 8 + j;
      atomicAdd(&cs[col], v);
      atomicAdd(&cs[64 + col], q);
    }
  }
#pragma unroll
  for (int j = 0; j < 8; ++j) {
    float v = yn[j], q = yn[j] * yn[j];
#pragma unroll
    for (int m = 4; m < 64; m <<= 1) { v += __shfl_xor(v, m); q += __shfl_xor(q, m); }
    if (lane < 4) {
      const int col = o + g * 8 + j;
      atomicAdd(&cs[col], v);
      atomicAdd(&cs[64 + col], q);
    }
  }
  __syncthreads();
  if (tid < 64) {
    atomicAdd(&stats_out[tid], cs[tid]);
    atomicAdd(&stats_out[64 + tid], cs[64 + tid]);
  }
}

__global__ void stats_kernel(const float* __restrict__ raw,
                             const float* __restrict__ lg,
                             const float* __restrict__ beta,
                             float* __restrict__ param,
                             float* __restrict__ ld_scalar) {
  const int t = threadIdx.x;
  const float S = raw[t], SS = raw[64 + t];
  const float mean = S / (float)BROWS;
  const float var = (SS - S * mean) / (float)(BROWS - 1);
  const float inv = rsqrtf(var + EPSV);
  const float g = __expf(lg[t]);
  const float A = g * inv;
  param[t] = A;
  param[64 + t] = beta[t] - mean * A;
  float contrib = lg[t] - 0.5f * __logf(var + EPSV);
  contrib += __shfl_xor(contrib, 1);  contrib += __shfl_xor(contrib, 2);
  contrib += __shfl_xor(contrib, 4);  contrib += __shfl_xor(contrib, 8);
  contrib += __shfl_xor(contrib, 16); contrib += __shfl_xor(contrib, 32);
  if (t == 0) atomicAdd(ld_scalar, contrib);
}

__global__ void final_kernel(float* __restrict__ out,
                             const float* __restrict__ param7,
                             const float* __restrict__ ld_scalar) {
  const size_t gid = (size_t)blockIdx.x * 256 + threadIdx.x;
  const size_t total = (size_t)BROWS * 64;
  const int col = gid & 63;
  const float z = out[gid];
  out[gid] = param7[col] * z + param7[64 + col];
  if (gid < BROWS) out[total + gid] += ld_scalar[0];
}

__global__ void pack_weights(const float* __restrict__ sW0,
                             const float* __restrict__ sWh,
                             const float* __restrict__ sWo,
                             const float* __restrict__ tW0,
                             const float* __restrict__ tWh,
                             const float* __restrict__ tWo,
                             __bf16* __restrict__ dst) {
  const int gid = blockIdx.x * 256 + threadIdx.x;
  const int gpn = PACK_NET / 8;
  const int b = gid / (2 * gpn);
  const int r = gid % (2 * gpn);
  const int net = r / gpn;
  const size_t o = (size_t)(r % gpn) * 8;
  const float* W0 = net ? tW0 : sW0;
  const float* Wh = net ? tWh : sWh;
  const float* Wo = net ? tWo : sWo;
  __bf16* d = dst + ((size_t)b * 2 + net) * PACK_NET + o;
  float v[8];
  if (o < PACK_H) {
    const int lane = (int)(o >> 3) & 63, nt = (int)(o >> 9) & 3, w = (int)(o >> 11);
    const int cc = lane & 15, q = lane >> 4;
    const int col = w * 64 + nt * 16 + cc;
    const float* s = W0 + (size_t)b * 32 * 512;
#pragma unroll
    for (int j = 0; j < 8; ++j) v[j] = s[(size_t)(q * 8 + j) * 512 + col];
  } else if (o < PACK_HEAD) {
    const size_t oo = o - PACK_H;
    const int l = (int)(oo >> 18);
    const int rr = (int)(oo & 262143);
    const int lane = (rr >> 3) & 63, nt = (rr >> 9) & 3, kt = (rr >> 11) & 15,
              w = rr >> 15;
    const int cc = lane & 15, q = lane >> 4;
    const int col = w * 64 + nt * 16 + cc;
    const float* s = Wh + ((size_t)(b * 3 + l)) * 512 * 512;
#pragma unroll
    for (int j = 0; j < 8; ++j) v[j] = s[(size_t)(kt * 32 + q * 8 + j) * 512 + col];
  } else {
    const size_t oo = o - PACK_HEAD;
    const int lane = (int)(oo >> 3) & 63, nt = (int)(oo >> 9) & 1, kt = (int)(oo >> 10);
    const int cc = lane & 15, q = lane >> 4;
    const int col = nt * 16 + cc;
    const float* s = Wo + (size_t)b * 512 * 32;
#pragma unroll
    for (int j = 0; j < 8; ++j) v[j] = s[(size_t)(kt * 32 + q * 8 + j) * 32 + col];
  }
  bf16x8 pv;
#pragma unroll
  for (int j = 0; j < 8; ++j) pv[j] = (__bf16)v[j];
  *(bf16x8*)d = pv;
}

extern "C" void kernel_launch(void* const* d_in, const int* in_sizes, int n_in,
                              void* d_out, int out_size, void* d_ws, size_t ws_size,
                              hipStream_t stream) {
  const float* y_in = (const float*)d_in[0];
  const float* sW0 = (const float*)d_in[1];
  const float* sb0 = (const float*)d_in[2];
  const float* sWh = (const float*)d_in[3];
  const float* sbh = (const float*)d_in[4];
  const float* sWo = (const float*)d_in[5];
  const float* sbo = (const float*)d_in[6];
  const float* tW0 = (const float*)d_in[7];
  const float* tb0 = (const float*)d_in[8];
  const float* tWh = (const float*)d_in[9];
  const float* tbh = (const float*)d_in[10];
  const float* tWo = (const float*)d_in[11];
  const float* tbo = (const float*)d_in[12];
  const float* bn_lg = (const float*)d_in[13];
  const float* bn_bt = (const float*)d_in[14];

  char* p = (char*)d_ws;
  __bf16* packed = (__bf16*)p; p += (size_t)NBLK * 2 * PACK_NET * 2;
  float* stats_raw = (float*)p; p += NBLK * 128 * 4;
  float* ld_scalar = (float*)p; p += 16;
  float* stats_param = (float*)p; p += NBLK * 128 * 4;
  const size_t base_used = (size_t)(p - (char*)d_ws);

  int NCH = 1;
  while (NCH < 32) {
    const size_t Rr = (size_t)BROWS / NCH;
    if (base_used + Rr * (1024 + 128 + 128) + 256 <= ws_size) break;
    NCH <<= 1;
  }
  const size_t R = (size_t)BROWS / NCH;
  __bf16* hg = (__bf16*)p; p += R * 512 * 2;
  float* souts = (float*)p; p += R * 32 * 4;
  float* touts = (float*)p; p += R * 32 * 4;

  float* out = (float*)d_out;
  float* zbuf = out;
  float* ld = out + (size_t)BROWS * 64;

  pack_weights<<<(NBLK * 2 * PACK_NET / 8) / 256, 256, 0, stream>>>(
      sW0, sWh, sWo, tW0, tWh, tWo, packed);
  hipMemsetAsync(stats_raw, 0, NBLK * 128 * 4 + 16, stream);

  const int gg = (int)(R / WROWS);
  const int gc = (int)(R / 64);

  for (int b = 0; b < NBLK; ++b) {
    const int o = (b & 1) ? 32 : 0;
    const __bf16* pwS = packed + (size_t)b * 2 * PACK_NET;
    const __bf16* pwT = pwS + PACK_NET;
    const float* prevP = stats_param + (size_t)(b - 1) * 128;
    float* praw = stats_raw + b * 128;
    const float* src = (b == 0) ? y_in : zbuf;

    for (int ch = 0; ch < NCH; ++ch) {
      const int r0 = (int)(ch * R);
      __bf16* hga = hg - (size_t)r0 * 512;          // absolute-row adjusted
      float* sa = souts - (size_t)r0 * 32;
      float* ta = touts - (size_t)r0 * 32;

      if (b == 0)
        mlp_front<1, true><<<gg, 512, 0, stream>>>(src, pwS, sb0 + b * 512,
            sbh + b * 1536, nullptr, hga, o, r0);
      else
        mlp_front<1, false><<<gg, 512, 0, stream>>>(src, pwS, sb0 + b * 512,
            sbh + b * 1536, prevP, hga, o, r0);
      mlp_mid<1><<<gg, 512, 0, stream>>>(pwS + PACK_H + 262144,
          sbh + b * 1536 + 512, hga, r0);
      mlp_back<1><<<gg, 512, 0, stream>>>(pwS + PACK_H + 2 * 262144,
          sbh + b * 1536 + 1024, pwS + PACK_HEAD, sbo + b * 32, hga, sa, r0);

      if (b == 0)
        mlp_front<2, true><<<gg, 512, 0, stream>>>(src, pwT, tb0 + b * 512,
            tbh + b * 1536, nullptr, hga, o, r0);
      else
        mlp_front<2, false><<<gg, 512, 0, stream>>>(src, pwT, tb0 + b * 512,
            tbh + b * 1536, prevP, hga, o, r0);
      mlp_mid<2><<<gg, 512, 0, stream>>>(pwT + PACK_H + 262144,
          tbh + b * 1536 + 512, hga, r0);
      mlp_back<2><<<gg, 512, 0, stream>>>(pwT + PACK_H + 2 * 262144,
          tbh + b * 1536 + 1024, pwT + PACK_HEAD, tbo + b * 32, hga, ta, r0);

      if (b == 0)
        combine_kernel<true><<<gc, 256, 0, stream>>>(src, sa, ta, nullptr,
            zbuf, ld, praw, o, r0);
      else
        combine_kernel<false><<<gc, 256, 0, stream>>>(src, sa, ta, prevP,
            zbuf, ld, praw, o, r0);
    }
    stats_kernel<<<1, 64, 0, stream>>>(praw, bn_lg + b * 64, bn_bt + b * 64,
                                       stats_param + (size_t)b * 128, ld_scalar);
  }

  final_kernel<<<(BROWS * 64) / 256, 256, 0, stream>>>(
      out, stats_param + 7 * 128, ld_scalar);
}

// Round 5
// 6448.675 us; speedup vs baseline: 2.3188x; 1.1052x over previous
//
#include <hip/hip_runtime.h>

#define NBLK 8
#define BROWS 131072
#define HDIM 512
#define EPSV 1e-5f
#define WROWS 128

typedef __bf16 bf16x8 __attribute__((ext_vector_type(8)));
typedef __bf16 bf16x4 __attribute__((ext_vector_type(4)));
typedef float f32x4 __attribute__((ext_vector_type(4)));

// packed net stream (elems): l0 16384 | 3 hidden x 262144 | head 16384
#define PACK_NET 819200
#define PACK_H 16384
#define PACK_HEAD 802816

__device__ __forceinline__ float act_tanh_f(float x) {
  // tanh(x) = 1 - 2/(exp(2x)+1); rcp is plenty accurate vs bf16 storage
  float e = __expf(x + x);
  return fmaf(-2.f, __builtin_amdgcn_rcpf(e + 1.f), 1.f);
}

template <int ACT>
__device__ __forceinline__ float apply_act(float v) {
  if (ACT == 1) return act_tanh_f(v);
  return fmaxf(v, 0.f);
}

// ---- hidden layer, operand-swapped: D[feature][batchrow] -------------------
// 16 waves; wave w owns output features [32w, 32w+32). hbuf in place.
template <int ACT>
__device__ __forceinline__ void dense_hidden(const __bf16* __restrict__ Wp,
                                             const float* __restrict__ bias,
                                             __bf16* hb, int w, int c,
                                             int quad, int lane) {
  f32x4 acc[8][2];
#pragma unroll
  for (int rb = 0; rb < 8; ++rb) {
    acc[rb][0] = (f32x4){0.f, 0.f, 0.f, 0.f};
    acc[rb][1] = (f32x4){0.f, 0.f, 0.f, 0.f};
  }
  const __bf16* wp = Wp + (size_t)w * 16384 + lane * 8;
  bf16x8 br[3][2];
#pragma unroll
  for (int s = 0; s < 2; ++s) {
    br[s][0] = *(const bf16x8*)(wp + s * 1024);
    br[s][1] = *(const bf16x8*)(wp + s * 1024 + 512);
  }
  const int msk = (c & 7) << 3;
#pragma unroll
  for (int kt = 0; kt < 16; ++kt) {
    if (kt + 2 < 16) {
      br[(kt + 2) % 3][0] = *(const bf16x8*)(wp + (kt + 2) * 1024);
      br[(kt + 2) % 3][1] = *(const bf16x8*)(wp + (kt + 2) * 1024 + 512);
    }
    const int sk = (kt * 32 + quad * 8) ^ msk;
#pragma unroll
    for (int rb = 0; rb < 8; ++rb) {
      bf16x8 hv = *(const bf16x8*)&hb[(rb * 16 + c) * HDIM + sk];
      acc[rb][0] = __builtin_amdgcn_mfma_f32_16x16x32_bf16(br[kt % 3][0], hv, acc[rb][0], 0, 0, 0);
      acc[rb][1] = __builtin_amdgcn_mfma_f32_16x16x32_bf16(br[kt % 3][1], hv, acc[rb][1], 0, 0, 0);
    }
  }
  __syncthreads();  // all hbuf reads done -> safe to overwrite in place
  f32x4 bi0 = *(const f32x4*)&bias[w * 32 + quad * 4];
  f32x4 bi1 = *(const f32x4*)&bias[w * 32 + 16 + quad * 4];
#pragma unroll
  for (int fb = 0; fb < 2; ++fb) {
    const f32x4 bi = fb ? bi1 : bi0;
    const int fsw = (w * 32 + fb * 16 + quad * 4) ^ msk;
#pragma unroll
    for (int rb = 0; rb < 8; ++rb) {
      bf16x4 pk;
#pragma unroll
      for (int i = 0; i < 4; ++i)
        pk[i] = (__bf16)apply_act<ACT>(acc[rb][fb][i] + bi[i]);
      *(bf16x4*)&hb[(rb * 16 + c) * HDIM + fsw] = pk;
    }
  }
  __syncthreads();
}

// ---- kernel A: l0 + hidden0 + hidden1 -> hg --------------------------------
template <int ACT, bool FIRST>
__global__ __launch_bounds__(1024) void mlp_A(
    const float* __restrict__ src, const __bf16* __restrict__ pw,
    const float* __restrict__ b0, const float* __restrict__ bh,
    const float* __restrict__ prevP, __bf16* __restrict__ hg, int o) {
  __shared__ __bf16 hbuf[WROWS * HDIM];  // 128 KiB
  const int tid = threadIdx.x;
  const int w = tid >> 6, lane = tid & 63, c = lane & 15, quad = lane >> 4;
  const size_t row0 = (size_t)blockIdx.x * WROWS;
  const int msk = (c & 7) << 3;

  {  // layer 0 (K=32, one MFMA step), ys read straight from global + BN
    float pa[8], pc8[8];
#pragma unroll
    for (int j = 0; j < 8; ++j) {
      pa[j] = FIRST ? 1.f : prevP[o + quad * 8 + j];
      pc8[j] = FIRST ? 0.f : prevP[64 + o + quad * 8 + j];
    }
    bf16x8 aw0 = *(const bf16x8*)&pw[(size_t)w * 1024 + lane * 8];
    bf16x8 aw1 = *(const bf16x8*)&pw[(size_t)w * 1024 + 512 + lane * 8];
    f32x4 acc[8][2];
#pragma unroll
    for (int rb = 0; rb < 8; ++rb) {
      acc[rb][0] = (f32x4){0.f, 0.f, 0.f, 0.f};
      acc[rb][1] = (f32x4){0.f, 0.f, 0.f, 0.f};
    }
#pragma unroll
    for (int rb = 0; rb < 8; ++rb) {
      const size_t r = row0 + rb * 16 + c;
      const float* p = &src[r * 64 + o + quad * 8];
      f32x4 y0 = *(const f32x4*)p;
      f32x4 y1 = *(const f32x4*)(p + 4);
      bf16x8 yb;
#pragma unroll
      for (int j = 0; j < 4; ++j) yb[j] = (__bf16)fmaf(pa[j], y0[j], pc8[j]);
#pragma unroll
      for (int j = 0; j < 4; ++j) yb[4 + j] = (__bf16)fmaf(pa[4 + j], y1[j], pc8[4 + j]);
      acc[rb][0] = __builtin_amdgcn_mfma_f32_16x16x32_bf16(aw0, yb, acc[rb][0], 0, 0, 0);
      acc[rb][1] = __builtin_amdgcn_mfma_f32_16x16x32_bf16(aw1, yb, acc[rb][1], 0, 0, 0);
    }
    f32x4 bi0 = *(const f32x4*)&b0[w * 32 + quad * 4];
    f32x4 bi1 = *(const f32x4*)&b0[w * 32 + 16 + quad * 4];
#pragma unroll
    for (int fb = 0; fb < 2; ++fb) {
      const f32x4 bi = fb ? bi1 : bi0;
      const int fsw = (w * 32 + fb * 16 + quad * 4) ^ msk;
#pragma unroll
      for (int rb = 0; rb < 8; ++rb) {
        bf16x4 pk;
#pragma unroll
        for (int i = 0; i < 4; ++i)
          pk[i] = (__bf16)apply_act<ACT>(acc[rb][fb][i] + bi[i]);
        *(bf16x4*)&hbuf[(rb * 16 + c) * HDIM + fsw] = pk;
      }
    }
  }
  __syncthreads();

  dense_hidden<ACT>(pw + PACK_H, bh, hbuf, w, c, quad, lane);
  dense_hidden<ACT>(pw + PACK_H + 262144, bh + 512, hbuf, w, c, quad, lane);

  // copy out (wave w: rows 8w..8w+7), unswizzle -> plain [row][k]
#pragma unroll
  for (int i = 0; i < 8; ++i) {
    const int row = w * 8 + i;
    bf16x8 v = *(const bf16x8*)&hbuf[row * HDIM + ((lane * 8) ^ ((row & 7) << 3))];
    *(bf16x8*)&hg[(row0 + row) * HDIM + lane * 8] = v;
  }
}

// ---- kernel B: hidden2 + head (+ fused combine on s-pass) ------------------
template <int ACT, bool SPASS, bool FIRST>
__global__ __launch_bounds__(1024) void mlp_B(
    const float* __restrict__ src, const __bf16* __restrict__ hgin,
    const __bf16* __restrict__ pw, const float* __restrict__ bh,
    const __bf16* __restrict__ ph, const float* __restrict__ bo,
    const float* __restrict__ prevP, float* __restrict__ touts,
    float* __restrict__ zbuf, float* __restrict__ ld,
    float* __restrict__ stats_out, int o) {
  __shared__ __bf16 hbuf[WROWS * HDIM];  // 128 KiB
  const int tid = threadIdx.x;
  const int w = tid >> 6, lane = tid & 63, c = lane & 15, quad = lane >> 4;
  const size_t row0 = (size_t)blockIdx.x * WROWS;
  const int msk = (c & 7) << 3;

  // stage in (wave w: rows 8w..8w+7), swizzle on LDS write
#pragma unroll
  for (int i = 0; i < 8; ++i) {
    const int row = w * 8 + i;
    bf16x8 v = *(const bf16x8*)&hgin[(row0 + row) * HDIM + lane * 8];
    *(bf16x8*)&hbuf[row * HDIM + ((lane * 8) ^ ((row & 7) << 3))] = v;
  }
  __syncthreads();

  dense_hidden<ACT>(pw, bh, hbuf, w, c, quad, lane);

  // head: wave w -> tile (fb = w&1 feature-half, rb = w>>1 row-block)
  const int fb = w & 1, rb = w >> 1;
  const __bf16* wp = ph + (size_t)fb * 8192 + lane * 8;
  bf16x8 hr[3];
  hr[0] = *(const bf16x8*)wp;
  hr[1] = *(const bf16x8*)(wp + 512);
  f32x4 acc = (f32x4){0.f, 0.f, 0.f, 0.f};
#pragma unroll
  for (int kt = 0; kt < 16; ++kt) {
    if (kt + 2 < 16) hr[(kt + 2) % 3] = *(const bf16x8*)(wp + (kt + 2) * 512);
    bf16x8 hv = *(const bf16x8*)&hbuf[(rb * 16 + c) * HDIM + ((kt * 32 + quad * 8) ^ msk)];
    acc = __builtin_amdgcn_mfma_f32_16x16x32_bf16(hr[kt % 3], hv, acc, 0, 0, 0);
  }
  const int f0 = fb * 16 + quad * 4;
  f32x4 bo4 = *(const f32x4*)&bo[f0];
  float sv[4];
#pragma unroll
  for (int i = 0; i < 4; ++i) sv[i] = acc[i] + bo4[i];
  const int r = rb * 16 + c;
  const size_t grow = row0 + r;

  if (!SPASS) {
    f32x4 ov = {sv[0], sv[1], sv[2], sv[3]};
    *(f32x4*)&touts[grow * 32 + f0] = ov;
    return;
  }

  // ---- s-pass: fused coupling + batchnorm stats ----
  __syncthreads();  // head's hbuf reads done; reuse as scratch
  float* cs = (float*)hbuf;   // [128]: col sum | col sumsq
  float* lda = cs + 128;      // [128]: per-row logdet partials
  if (tid < 256) cs[tid] = 0.f;
  __syncthreads();

  const int oc = o ^ 32;
  f32x4 tv = *(const f32x4*)&touts[grow * 32 + f0];
  float zc[4], yn2[4];
  {
    f32x4 pA1, pC1, pA2, pC2;
    if (FIRST) {
      pA1 = pA2 = (f32x4){1.f, 1.f, 1.f, 1.f};
      pC1 = pC2 = (f32x4){0.f, 0.f, 0.f, 0.f};
    } else {
      pA1 = *(const f32x4*)&prevP[oc + f0];
      pC1 = *(const f32x4*)&prevP[64 + oc + f0];
      pA2 = *(const f32x4*)&prevP[o + f0];
      pC2 = *(const f32x4*)&prevP[64 + o + f0];
    }
    f32x4 yv = *(const f32x4*)&src[grow * 64 + oc + f0];
    f32x4 zo;
#pragma unroll
    for (int i = 0; i < 4; ++i) {
      zc[i] = fmaf(fmaf(pA1[i], yv[i], pC1[i]), __expf(sv[i]), tv[i]);
      zo[i] = zc[i];
    }
    *(f32x4*)&zbuf[grow * 64 + oc + f0] = zo;
    f32x4 yv2 = *(const f32x4*)&src[grow * 64 + o + f0];
    f32x4 yo;
#pragma unroll
    for (int i = 0; i < 4; ++i) {
      yn2[i] = fmaf(pA2[i], yv2[i], pC2[i]);
      yo[i] = yn2[i];
    }
    *(f32x4*)&zbuf[grow * 64 + o + f0] = yo;
  }

  // per-row logdet partial (sum of s over this wave's 4 features x 4 quads)
  {
    float ssum = sv[0] + sv[1] + sv[2] + sv[3];
    ssum += __shfl_xor(ssum, 16);
    ssum += __shfl_xor(ssum, 32);
    if (quad == 0) atomicAdd(&lda[r], ssum);
  }

  // column stats: reduce over the 16 c-lanes, then LDS atomics
#pragma unroll
  for (int i = 0; i < 4; ++i) {
    float v = zc[i], q = zc[i] * zc[i];
    float v2 = yn2[i], q2 = yn2[i] * yn2[i];
#pragma unroll
    for (int m = 1; m < 16; m <<= 1) {
      v += __shfl_xor(v, m);  q += __shfl_xor(q, m);
      v2 += __shfl_xor(v2, m); q2 += __shfl_xor(q2, m);
    }
    if (c == 0) {
      atomicAdd(&cs[oc + f0 + i], v);
      atomicAdd(&cs[64 + oc + f0 + i], q);
      atomicAdd(&cs[o + f0 + i], v2);
      atomicAdd(&cs[64 + o + f0 + i], q2);
    }
  }
  __syncthreads();
  if (tid < 128) {
    atomicAdd(&stats_out[tid], cs[tid]);
  } else if (tid < 256) {
    const int rr = tid - 128;
    const size_t gr = row0 + rr;
    if (FIRST) ld[gr] = lda[rr]; else ld[gr] += lda[rr];
  }
}

// ---- small kernels ----------------------------------------------------------

__global__ void stats_kernel(const float* __restrict__ raw,
                             const float* __restrict__ lg,
                             const float* __restrict__ beta,
                             float* __restrict__ param,
                             float* __restrict__ ld_scalar) {
  const int t = threadIdx.x;  // 64
  const float S = raw[t], SS = raw[64 + t];
  const float mean = S / (float)BROWS;
  const float var = (SS - S * mean) / (float)(BROWS - 1);
  const float inv = rsqrtf(var + EPSV);
  const float g = __expf(lg[t]);
  const float A = g * inv;
  param[t] = A;
  param[64 + t] = beta[t] - mean * A;
  float contrib = lg[t] - 0.5f * __logf(var + EPSV);
  contrib += __shfl_xor(contrib, 1);  contrib += __shfl_xor(contrib, 2);
  contrib += __shfl_xor(contrib, 4);  contrib += __shfl_xor(contrib, 8);
  contrib += __shfl_xor(contrib, 16); contrib += __shfl_xor(contrib, 32);
  if (t == 0) atomicAdd(ld_scalar, contrib);
}

__global__ void final_kernel(float* __restrict__ out,
                             const float* __restrict__ param7,
                             const float* __restrict__ ld_scalar) {
  const size_t gid = (size_t)blockIdx.x * 256 + threadIdx.x;
  const size_t total = (size_t)BROWS * 64;
  const int col = gid & 63;
  const float z = out[gid];
  out[gid] = param7[col] * z + param7[64 + col];
  if (gid < BROWS) out[total + gid] += ld_scalar[0];
}

// ---- pack weights: A-operand fragment streams -------------------------------
// per net: l0 [w16][fb2][lane64][8] | hidden l [w16][kt16][fb2][lane64][8]
//        | head [fb2][kt16][lane64][8]
__global__ void pack_weights(const float* __restrict__ sW0,
                             const float* __restrict__ sWh,
                             const float* __restrict__ sWo,
                             const float* __restrict__ tW0,
                             const float* __restrict__ tWh,
                             const float* __restrict__ tWo,
                             __bf16* __restrict__ dst) {
  const int gid = blockIdx.x * 256 + threadIdx.x;
  const int gpn = PACK_NET / 8;
  const int b = gid / (2 * gpn);
  const int rr0 = gid % (2 * gpn);
  const int net = rr0 / gpn;
  const size_t o = (size_t)(rr0 % gpn) * 8;
  const float* W0 = net ? tW0 : sW0;
  const float* Wh = net ? tWh : sWh;
  const float* Wo = net ? tWo : sWo;
  __bf16* d = dst + ((size_t)b * 2 + net) * PACK_NET + o;
  float v[8];
  if (o < PACK_H) {  // l0: K=32
    const int idx = (int)(o >> 3);
    const int lane = idx & 63, fbb = (idx >> 6) & 1, w = (idx >> 7) & 15;
    const int cc = lane & 15, q = lane >> 4;
    const int f = w * 32 + fbb * 16 + cc;
    const float* s = W0 + (size_t)b * 32 * 512;
#pragma unroll
    for (int j = 0; j < 8; ++j) v[j] = s[(size_t)(q * 8 + j) * 512 + f];
  } else if (o < PACK_HEAD) {  // hidden
    const size_t oo = o - PACK_H;
    const int l = (int)(oo >> 18);
    const int idx = (int)((oo & 262143) >> 3);
    const int lane = idx & 63, fbb = (idx >> 6) & 1, kt = (idx >> 7) & 15,
              w = (idx >> 11) & 15;
    const int cc = lane & 15, q = lane >> 4;
    const int f = w * 32 + fbb * 16 + cc;
    const float* s = Wh + ((size_t)(b * 3 + l)) * 512 * 512;
#pragma unroll
    for (int j = 0; j < 8; ++j) v[j] = s[(size_t)(kt * 32 + q * 8 + j) * 512 + f];
  } else {  // head
    const size_t oo = o - PACK_HEAD;
    const int idx = (int)(oo >> 3);
    const int lane = idx & 63, kt = (idx >> 6) & 15, fbb = (idx >> 10) & 1;
    const int cc = lane & 15, q = lane >> 4;
    const int f = fbb * 16 + cc;
    const float* s = Wo + (size_t)b * 512 * 32;
#pragma unroll
    for (int j = 0; j < 8; ++j) v[j] = s[(size_t)(kt * 32 + q * 8 + j) * 32 + f];
  }
  bf16x8 pv;
#pragma unroll
  for (int j = 0; j < 8; ++j) pv[j] = (__bf16)v[j];
  *(bf16x8*)d = pv;
}

// ---- launcher ---------------------------------------------------------------

extern "C" void kernel_launch(void* const* d_in, const int* in_sizes, int n_in,
                              void* d_out, int out_size, void* d_ws, size_t ws_size,
                              hipStream_t stream) {
  const float* y_in = (const float*)d_in[0];
  const float* sW0 = (const float*)d_in[1];
  const float* sb0 = (const float*)d_in[2];
  const float* sWh = (const float*)d_in[3];
  const float* sbh = (const float*)d_in[4];
  const float* sWo = (const float*)d_in[5];
  const float* sbo = (const float*)d_in[6];
  const float* tW0 = (const float*)d_in[7];
  const float* tb0 = (const float*)d_in[8];
  const float* tWh = (const float*)d_in[9];
  const float* tbh = (const float*)d_in[10];
  const float* tWo = (const float*)d_in[11];
  const float* tbo = (const float*)d_in[12];
  const float* bn_lg = (const float*)d_in[13];
  const float* bn_bt = (const float*)d_in[14];

  char* p = (char*)d_ws;
  __bf16* packed = (__bf16*)p; p += (size_t)NBLK * 2 * PACK_NET * 2;
  float* stats_raw = (float*)p; p += NBLK * 128 * 4;
  float* ld_scalar = (float*)p; p += 16;
  float* stats_param = (float*)p; p += NBLK * 128 * 4;
  __bf16* hg = (__bf16*)p; p += (size_t)BROWS * HDIM * 2;   // 134 MB
  float* touts = (float*)p; p += (size_t)BROWS * 32 * 4;    // 16.8 MB

  float* out = (float*)d_out;
  float* zbuf = out;
  float* ld = out + (size_t)BROWS * 64;

  pack_weights<<<(NBLK * 2 * PACK_NET / 8) / 256, 256, 0, stream>>>(
      sW0, sWh, sWo, tW0, tWh, tWo, packed);
  hipMemsetAsync(stats_raw, 0, NBLK * 128 * 4 + 16, stream);

  const int GG = BROWS / WROWS;  // 1024 wgs

  for (int b = 0; b < NBLK; ++b) {
    const int o = (b & 1) ? 32 : 0;
    const __bf16* pwS = packed + (size_t)b * 2 * PACK_NET;
    const __bf16* pwT = pwS + PACK_NET;
    const float* prevP = stats_param + (size_t)(b - 1) * 128;
    float* praw = stats_raw + b * 128;
    const float* src = (b == 0) ? y_in : zbuf;

    if (b == 0) {
      mlp_A<2, true><<<GG, 1024, 0, stream>>>(src, pwT, tb0, tbh, nullptr, hg, o);
      mlp_B<2, false, true><<<GG, 1024, 0, stream>>>(src, hg,
          pwT + PACK_H + 2 * 262144, tbh + 1024, pwT + PACK_HEAD, tbo,
          nullptr, touts, zbuf, ld, praw, o);
      mlp_A<1, true><<<GG, 1024, 0, stream>>>(src, pwS, sb0, sbh, nullptr, hg, o);
      mlp_B<1, true, true><<<GG, 1024, 0, stream>>>(src, hg,
          pwS + PACK_H + 2 * 262144, sbh + 1024, pwS + PACK_HEAD, sbo,
          nullptr, touts, zbuf, ld, praw, o);
    } else {
      mlp_A<2, false><<<GG, 1024, 0, stream>>>(src, pwT, tb0 + b * 512,
          tbh + b * 1536, prevP, hg, o);
      mlp_B<2, false, false><<<GG, 1024, 0, stream>>>(src, hg,
          pwT + PACK_H + 2 * 262144, tbh + b * 1536 + 1024, pwT + PACK_HEAD,
          tbo + b * 32, prevP, touts, zbuf, ld, praw, o);
      mlp_A<1, false><<<GG, 1024, 0, stream>>>(src, pwS, sb0 + b * 512,
          sbh + b * 1536, prevP, hg, o);
      mlp_B<1, true, false><<<GG, 1024, 0, stream>>>(src, hg,
          pwS + PACK_H + 2 * 262144, sbh + b * 1536 + 1024, pwS + PACK_HEAD,
          sbo + b * 32, prevP, touts, zbuf, ld, praw, o);
    }
    stats_kernel<<<1, 64, 0, stream>>>(praw, bn_lg + b * 64, bn_bt + b * 64,
                                       stats_param + (size_t)b * 128, ld_scalar);
  }

  final_kernel<<<(BROWS * 64) / 256, 256, 0, stream>>>(
      out, stats_param + 7 * 128, ld_scalar);
}

// Round 6
// 5585.998 us; speedup vs baseline: 2.6769x; 1.1544x over previous
//
#include <hip/hip_runtime.h>

#define NBLK 8
#define BROWS 131072
#define HDIM 512
#define EPSV 1e-5f
#define WROWS 128

typedef __bf16 bf16x8 __attribute__((ext_vector_type(8)));
typedef __bf16 bf16x4 __attribute__((ext_vector_type(4)));
typedef float f32x4 __attribute__((ext_vector_type(4)));

// packed net stream (elems): l0 16384 | 3 hidden x 262144 | head 16384
#define PACK_NET 819200
#define PACK_H 16384
#define PACK_HEAD 802816

__device__ __forceinline__ float act_tanh_f(float x) {
  // tanh(x) = 1 - 2/(exp(2x)+1); rcp is plenty accurate vs bf16 storage
  float e = __expf(x + x);
  return fmaf(-2.f, __builtin_amdgcn_rcpf(e + 1.f), 1.f);
}

template <int ACT>
__device__ __forceinline__ float apply_act(float v) {
  if (ACT == 1) return act_tanh_f(v);
  return fmaxf(v, 0.f);
}

// ---- hidden layer, operand-swapped: D[feature][batchrow] -------------------
// 16 waves; wave w owns output features [32w, 32w+32). hbuf in place.
template <int ACT>
__device__ __forceinline__ void dense_hidden(const __bf16* __restrict__ Wp,
                                             const float* __restrict__ bias,
                                             __bf16* hb, int w, int c,
                                             int quad, int lane) {
  f32x4 acc[8][2];
#pragma unroll
  for (int rb = 0; rb < 8; ++rb) {
    acc[rb][0] = (f32x4){0.f, 0.f, 0.f, 0.f};
    acc[rb][1] = (f32x4){0.f, 0.f, 0.f, 0.f};
  }
  const __bf16* wp = Wp + (size_t)w * 16384 + lane * 8;
  bf16x8 br[3][2];
#pragma unroll
  for (int s = 0; s < 2; ++s) {
    br[s][0] = *(const bf16x8*)(wp + s * 1024);
    br[s][1] = *(const bf16x8*)(wp + s * 1024 + 512);
  }
  const int msk = (c & 7) << 3;
#pragma unroll
  for (int kt = 0; kt < 16; ++kt) {
    if (kt + 2 < 16) {
      br[(kt + 2) % 3][0] = *(const bf16x8*)(wp + (kt + 2) * 1024);
      br[(kt + 2) % 3][1] = *(const bf16x8*)(wp + (kt + 2) * 1024 + 512);
    }
    const int sk = (kt * 32 + quad * 8) ^ msk;
#pragma unroll
    for (int rb = 0; rb < 8; ++rb) {
      bf16x8 hv = *(const bf16x8*)&hb[(rb * 16 + c) * HDIM + sk];
      acc[rb][0] = __builtin_amdgcn_mfma_f32_16x16x32_bf16(br[kt % 3][0], hv, acc[rb][0], 0, 0, 0);
      acc[rb][1] = __builtin_amdgcn_mfma_f32_16x16x32_bf16(br[kt % 3][1], hv, acc[rb][1], 0, 0, 0);
    }
  }
  __syncthreads();  // all hbuf reads done -> safe to overwrite in place
  f32x4 bi0 = *(const f32x4*)&bias[w * 32 + quad * 4];
  f32x4 bi1 = *(const f32x4*)&bias[w * 32 + 16 + quad * 4];
#pragma unroll
  for (int fb = 0; fb < 2; ++fb) {
    const f32x4 bi = fb ? bi1 : bi0;
    const int fsw = (w * 32 + fb * 16 + quad * 4) ^ msk;
#pragma unroll
    for (int rb = 0; rb < 8; ++rb) {
      bf16x4 pk;
#pragma unroll
      for (int i = 0; i < 4; ++i)
        pk[i] = (__bf16)apply_act<ACT>(acc[rb][fb][i] + bi[i]);
      *(bf16x4*)&hb[(rb * 16 + c) * HDIM + fsw] = pk;
    }
  }
  __syncthreads();
}

// ---- kernel A: l0 + hidden0 + hidden1 -> hg --------------------------------
template <int ACT, bool FIRST>
__global__ __launch_bounds__(1024, 4) void mlp_A(
    const float* __restrict__ src, const __bf16* __restrict__ pw,
    const float* __restrict__ b0, const float* __restrict__ bh,
    const float* __restrict__ prevP, __bf16* __restrict__ hg, int o) {
  __shared__ __bf16 hbuf[WROWS * HDIM];  // 128 KiB
  __shared__ __bf16 ysb[WROWS * 32];     // 8 KiB
  const int tid = threadIdx.x;
  const int w = tid >> 6, lane = tid & 63, c = lane & 15, quad = lane >> 4;
  const size_t row0 = (size_t)blockIdx.x * WROWS;
  const int msk = (c & 7) << 3;

  // stage normalized ys once: 128 rows x 32 cols, one global read per element
  {
    const int row = tid >> 3, sub = tid & 7;  // 128 rows x 8 subs x 4 cols
    const int col0 = o + sub * 4;
    f32x4 yv = *(const f32x4*)&src[(row0 + row) * 64 + col0];
    bf16x4 pv;
#pragma unroll
    for (int j = 0; j < 4; ++j) {
      const float A_ = FIRST ? 1.f : prevP[col0 + j];
      const float C_ = FIRST ? 0.f : prevP[64 + col0 + j];
      pv[j] = (__bf16)fmaf(A_, yv[j], C_);
    }
    *(bf16x4*)&ysb[row * 32 + ((sub * 4) ^ ((row & 3) << 3))] = pv;
  }
  __syncthreads();

  {  // layer 0 (K=32, one MFMA step per rb), ys from LDS
    bf16x8 aw0 = *(const bf16x8*)&pw[(size_t)w * 1024 + lane * 8];
    bf16x8 aw1 = *(const bf16x8*)&pw[(size_t)w * 1024 + 512 + lane * 8];
    f32x4 acc[8][2];
#pragma unroll
    for (int rb = 0; rb < 8; ++rb) {
      acc[rb][0] = (f32x4){0.f, 0.f, 0.f, 0.f};
      acc[rb][1] = (f32x4){0.f, 0.f, 0.f, 0.f};
    }
    const int ysk = (quad * 8) ^ ((c & 3) << 3);
#pragma unroll
    for (int rb = 0; rb < 8; ++rb) {
      bf16x8 yb = *(const bf16x8*)&ysb[(rb * 16 + c) * 32 + ysk];
      acc[rb][0] = __builtin_amdgcn_mfma_f32_16x16x32_bf16(aw0, yb, acc[rb][0], 0, 0, 0);
      acc[rb][1] = __builtin_amdgcn_mfma_f32_16x16x32_bf16(aw1, yb, acc[rb][1], 0, 0, 0);
    }
    f32x4 bi0 = *(const f32x4*)&b0[w * 32 + quad * 4];
    f32x4 bi1 = *(const f32x4*)&b0[w * 32 + 16 + quad * 4];
#pragma unroll
    for (int fb = 0; fb < 2; ++fb) {
      const f32x4 bi = fb ? bi1 : bi0;
      const int fsw = (w * 32 + fb * 16 + quad * 4) ^ msk;
#pragma unroll
      for (int rb = 0; rb < 8; ++rb) {
        bf16x4 pk;
#pragma unroll
        for (int i = 0; i < 4; ++i)
          pk[i] = (__bf16)apply_act<ACT>(acc[rb][fb][i] + bi[i]);
        *(bf16x4*)&hbuf[(rb * 16 + c) * HDIM + fsw] = pk;
      }
    }
  }
  __syncthreads();

  dense_hidden<ACT>(pw + PACK_H, bh, hbuf, w, c, quad, lane);
  dense_hidden<ACT>(pw + PACK_H + 262144, bh + 512, hbuf, w, c, quad, lane);

  // copy out (wave w: rows 8w..8w+7), unswizzle -> plain [row][k]
#pragma unroll
  for (int i = 0; i < 8; ++i) {
    const int row = w * 8 + i;
    bf16x8 v = *(const bf16x8*)&hbuf[row * HDIM + ((lane * 8) ^ ((row & 7) << 3))];
    *(bf16x8*)&hg[(row0 + row) * HDIM + lane * 8] = v;
  }
}

// ---- kernel B: hidden2 + head (+ fused combine on s-pass) ------------------
template <int ACT, bool SPASS, bool FIRST>
__global__ __launch_bounds__(1024, 4) void mlp_B(
    const float* __restrict__ src, const __bf16* __restrict__ hgin,
    const __bf16* __restrict__ pw, const float* __restrict__ bh,
    const __bf16* __restrict__ ph, const float* __restrict__ bo,
    const float* __restrict__ prevP, float* __restrict__ touts,
    float* __restrict__ zbuf, float* __restrict__ ld,
    float* __restrict__ stats_out, int o) {
  __shared__ __bf16 hbuf[WROWS * HDIM];  // 128 KiB
  const int tid = threadIdx.x;
  const int w = tid >> 6, lane = tid & 63, c = lane & 15, quad = lane >> 4;
  const size_t row0 = (size_t)blockIdx.x * WROWS;
  const int msk = (c & 7) << 3;

  // stage in (wave w: rows 8w..8w+7), swizzle on LDS write
#pragma unroll
  for (int i = 0; i < 8; ++i) {
    const int row = w * 8 + i;
    bf16x8 v = *(const bf16x8*)&hgin[(row0 + row) * HDIM + lane * 8];
    *(bf16x8*)&hbuf[row * HDIM + ((lane * 8) ^ ((row & 7) << 3))] = v;
  }
  __syncthreads();

  dense_hidden<ACT>(pw, bh, hbuf, w, c, quad, lane);

  // head: wave w -> tile (fb = w&1 feature-half, rb = w>>1 row-block)
  const int fb = w & 1, rb = w >> 1;
  const __bf16* wp = ph + (size_t)fb * 8192 + lane * 8;
  bf16x8 hr[3];
  hr[0] = *(const bf16x8*)wp;
  hr[1] = *(const bf16x8*)(wp + 512);
  f32x4 acc = (f32x4){0.f, 0.f, 0.f, 0.f};
#pragma unroll
  for (int kt = 0; kt < 16; ++kt) {
    if (kt + 2 < 16) hr[(kt + 2) % 3] = *(const bf16x8*)(wp + (kt + 2) * 512);
    bf16x8 hv = *(const bf16x8*)&hbuf[(rb * 16 + c) * HDIM + ((kt * 32 + quad * 8) ^ msk)];
    acc = __builtin_amdgcn_mfma_f32_16x16x32_bf16(hr[kt % 3], hv, acc, 0, 0, 0);
  }
  const int f0 = fb * 16 + quad * 4;
  f32x4 bo4 = *(const f32x4*)&bo[f0];
  float sv[4];
#pragma unroll
  for (int i = 0; i < 4; ++i) sv[i] = acc[i] + bo4[i];
  const int r = rb * 16 + c;
  const size_t grow = row0 + r;

  if (!SPASS) {
    f32x4 ov = {sv[0], sv[1], sv[2], sv[3]};
    *(f32x4*)&touts[grow * 32 + f0] = ov;
    return;
  }

  // ---- s-pass: fused coupling + batchnorm stats ----
  __syncthreads();  // head's hbuf reads done; reuse as scratch
  float* cs = (float*)hbuf;   // [128]: col sum | col sumsq
  float* lda = cs + 128;      // [128]: per-row logdet partials
  if (tid < 256) cs[tid] = 0.f;
  __syncthreads();

  const int oc = o ^ 32;
  f32x4 tv = *(const f32x4*)&touts[grow * 32 + f0];
  float zc[4], yn2[4];
  {
    f32x4 pA1, pC1, pA2, pC2;
    if (FIRST) {
      pA1 = pA2 = (f32x4){1.f, 1.f, 1.f, 1.f};
      pC1 = pC2 = (f32x4){0.f, 0.f, 0.f, 0.f};
    } else {
      pA1 = *(const f32x4*)&prevP[oc + f0];
      pC1 = *(const f32x4*)&prevP[64 + oc + f0];
      pA2 = *(const f32x4*)&prevP[o + f0];
      pC2 = *(const f32x4*)&prevP[64 + o + f0];
    }
    f32x4 yv = *(const f32x4*)&src[grow * 64 + oc + f0];
    f32x4 zo;
#pragma unroll
    for (int i = 0; i < 4; ++i) {
      zc[i] = fmaf(fmaf(pA1[i], yv[i], pC1[i]), __expf(sv[i]), tv[i]);
      zo[i] = zc[i];
    }
    *(f32x4*)&zbuf[grow * 64 + oc + f0] = zo;
    f32x4 yv2 = *(const f32x4*)&src[grow * 64 + o + f0];
    f32x4 yo;
#pragma unroll
    for (int i = 0; i < 4; ++i) {
      yn2[i] = fmaf(pA2[i], yv2[i], pC2[i]);
      yo[i] = yn2[i];
    }
    *(f32x4*)&zbuf[grow * 64 + o + f0] = yo;
  }

  // per-row logdet partial (sum of s over this wave's 4 features x 4 quads)
  {
    float ssum = sv[0] + sv[1] + sv[2] + sv[3];
    ssum += __shfl_xor(ssum, 16);
    ssum += __shfl_xor(ssum, 32);
    if (quad == 0) atomicAdd(&lda[r], ssum);
  }

  // column stats: reduce over the 16 c-lanes, then LDS atomics
#pragma unroll
  for (int i = 0; i < 4; ++i) {
    float v = zc[i], q = zc[i] * zc[i];
    float v2 = yn2[i], q2 = yn2[i] * yn2[i];
#pragma unroll
    for (int m = 1; m < 16; m <<= 1) {
      v += __shfl_xor(v, m);  q += __shfl_xor(q, m);
      v2 += __shfl_xor(v2, m); q2 += __shfl_xor(q2, m);
    }
    if (c == 0) {
      atomicAdd(&cs[oc + f0 + i], v);
      atomicAdd(&cs[64 + oc + f0 + i], q);
      atomicAdd(&cs[o + f0 + i], v2);
      atomicAdd(&cs[64 + o + f0 + i], q2);
    }
  }
  __syncthreads();
  if (tid < 128) {
    atomicAdd(&stats_out[tid], cs[tid]);
  } else if (tid < 256) {
    const int rr = tid - 128;
    const size_t gr = row0 + rr;
    if (FIRST) ld[gr] = lda[rr]; else ld[gr] += lda[rr];
  }
}

// ---- small kernels ----------------------------------------------------------

__global__ void stats_kernel(const float* __restrict__ raw,
                             const float* __restrict__ lg,
                             const float* __restrict__ beta,
                             float* __restrict__ param,
                             float* __restrict__ ld_scalar) {
  const int t = threadIdx.x;  // 64
  const float S = raw[t], SS = raw[64 + t];
  const float mean = S / (float)BROWS;
  const float var = (SS - S * mean) / (float)(BROWS - 1);
  const float inv = rsqrtf(var + EPSV);
  const float g = __expf(lg[t]);
  const float A = g * inv;
  param[t] = A;
  param[64 + t] = beta[t] - mean * A;
  float contrib = lg[t] - 0.5f * __logf(var + EPSV);
  contrib += __shfl_xor(contrib, 1);  contrib += __shfl_xor(contrib, 2);
  contrib += __shfl_xor(contrib, 4);  contrib += __shfl_xor(contrib, 8);
  contrib += __shfl_xor(contrib, 16); contrib += __shfl_xor(contrib, 32);
  if (t == 0) atomicAdd(ld_scalar, contrib);
}

__global__ void final_kernel(float* __restrict__ out,
                             const float* __restrict__ param7,
                             const float* __restrict__ ld_scalar) {
  const size_t gid = (size_t)blockIdx.x * 256 + threadIdx.x;
  const size_t total = (size_t)BROWS * 64;
  const int col = gid & 63;
  const float z = out[gid];
  out[gid] = param7[col] * z + param7[64 + col];
  if (gid < BROWS) out[total + gid] += ld_scalar[0];
}

// ---- pack weights: A-operand fragment streams -------------------------------
// per net: l0 [w16][fb2][lane64][8] | hidden l [w16][kt16][fb2][lane64][8]
//        | head [fb2][kt16][lane64][8]
__global__ void pack_weights(const float* __restrict__ sW0,
                             const float* __restrict__ sWh,
                             const float* __restrict__ sWo,
                             const float* __restrict__ tW0,
                             const float* __restrict__ tWh,
                             const float* __restrict__ tWo,
                             __bf16* __restrict__ dst) {
  const int gid = blockIdx.x * 256 + threadIdx.x;
  const int gpn = PACK_NET / 8;
  const int b = gid / (2 * gpn);
  const int rr0 = gid % (2 * gpn);
  const int net = rr0 / gpn;
  const size_t o = (size_t)(rr0 % gpn) * 8;
  const float* W0 = net ? tW0 : sW0;
  const float* Wh = net ? tWh : sWh;
  const float* Wo = net ? tWo : sWo;
  __bf16* d = dst + ((size_t)b * 2 + net) * PACK_NET + o;
  float v[8];
  if (o < PACK_H) {  // l0: K=32
    const int idx = (int)(o >> 3);
    const int lane = idx & 63, fbb = (idx >> 6) & 1, w = (idx >> 7) & 15;
    const int cc = lane & 15, q = lane >> 4;
    const int f = w * 32 + fbb * 16 + cc;
    const float* s = W0 + (size_t)b * 32 * 512;
#pragma unroll
    for (int j = 0; j < 8; ++j) v[j] = s[(size_t)(q * 8 + j) * 512 + f];
  } else if (o < PACK_HEAD) {  // hidden
    const size_t oo = o - PACK_H;
    const int l = (int)(oo >> 18);
    const int idx = (int)((oo & 262143) >> 3);
    const int lane = idx & 63, fbb = (idx >> 6) & 1, kt = (idx >> 7) & 15,
              w = (idx >> 11) & 15;
    const int cc = lane & 15, q = lane >> 4;
    const int f = w * 32 + fbb * 16 + cc;
    const float* s = Wh + ((size_t)(b * 3 + l)) * 512 * 512;
#pragma unroll
    for (int j = 0; j < 8; ++j) v[j] = s[(size_t)(kt * 32 + q * 8 + j) * 512 + f];
  } else {  // head
    const size_t oo = o - PACK_HEAD;
    const int idx = (int)(oo >> 3);
    const int lane = idx & 63, kt = (idx >> 6) & 15, fbb = (idx >> 10) & 1;
    const int cc = lane & 15, q = lane >> 4;
    const int f = fbb * 16 + cc;
    const float* s = Wo + (size_t)b * 512 * 32;
#pragma unroll
    for (int j = 0; j < 8; ++j) v[j] = s[(size_t)(kt * 32 + q * 8 + j) * 32 + f];
  }
  bf16x8 pv;
#pragma unroll
  for (int j = 0; j < 8; ++j) pv[j] = (__bf16)v[j];
  *(bf16x8*)d = pv;
}

// ---- launcher ---------------------------------------------------------------

extern "C" void kernel_launch(void* const* d_in, const int* in_sizes, int n_in,
                              void* d_out, int out_size, void* d_ws, size_t ws_size,
                              hipStream_t stream) {
  const float* y_in = (const float*)d_in[0];
  const float* sW0 = (const float*)d_in[1];
  const float* sb0 = (const float*)d_in[2];
  const float* sWh = (const float*)d_in[3];
  const float* sbh = (const float*)d_in[4];
  const float* sWo = (const float*)d_in[5];
  const float* sbo = (const float*)d_in[6];
  const float* tW0 = (const float*)d_in[7];
  const float* tb0 = (const float*)d_in[8];
  const float* tWh = (const float*)d_in[9];
  const float* tbh = (const float*)d_in[10];
  const float* tWo = (const float*)d_in[11];
  const float* tbo = (const float*)d_in[12];
  const float* bn_lg = (const float*)d_in[13];
  const float* bn_bt = (const float*)d_in[14];

  char* p = (char*)d_ws;
  __bf16* packed = (__bf16*)p; p += (size_t)NBLK * 2 * PACK_NET * 2;
  float* stats_raw = (float*)p; p += NBLK * 128 * 4;
  float* ld_scalar = (float*)p; p += 16;
  float* stats_param = (float*)p; p += NBLK * 128 * 4;
  __bf16* hg = (__bf16*)p; p += (size_t)BROWS * HDIM * 2;   // 134 MB
  float* touts = (float*)p; p += (size_t)BROWS * 32 * 4;    // 16.8 MB

  float* out = (float*)d_out;
  float* zbuf = out;
  float* ld = out + (size_t)BROWS * 64;

  pack_weights<<<(NBLK * 2 * PACK_NET / 8) / 256, 256, 0, stream>>>(
      sW0, sWh, sWo, tW0, tWh, tWo, packed);
  hipMemsetAsync(stats_raw, 0, NBLK * 128 * 4 + 16, stream);

  const int GG = BROWS / WROWS;  // 1024 wgs

  for (int b = 0; b < NBLK; ++b) {
    const int o = (b & 1) ? 32 : 0;
    const __bf16* pwS = packed + (size_t)b * 2 * PACK_NET;
    const __bf16* pwT = pwS + PACK_NET;
    const float* prevP = stats_param + (size_t)(b - 1) * 128;
    float* praw = stats_raw + b * 128;
    const float* src = (b == 0) ? y_in : zbuf;

    if (b == 0) {
      mlp_A<2, true><<<GG, 1024, 0, stream>>>(src, pwT, tb0, tbh, nullptr, hg, o);
      mlp_B<2, false, true><<<GG, 1024, 0, stream>>>(src, hg,
          pwT + PACK_H + 2 * 262144, tbh + 1024, pwT + PACK_HEAD, tbo,
          nullptr, touts, zbuf, ld, praw, o);
      mlp_A<1, true><<<GG, 1024, 0, stream>>>(src, pwS, sb0, sbh, nullptr, hg, o);
      mlp_B<1, true, true><<<GG, 1024, 0, stream>>>(src, hg,
          pwS + PACK_H + 2 * 262144, sbh + 1024, pwS + PACK_HEAD, sbo,
          nullptr, touts, zbuf, ld, praw, o);
    } else {
      mlp_A<2, false><<<GG, 1024, 0, stream>>>(src, pwT, tb0 + b * 512,
          tbh + b * 1536, prevP, hg, o);
      mlp_B<2, false, false><<<GG, 1024, 0, stream>>>(src, hg,
          pwT + PACK_H + 2 * 262144, tbh + b * 1536 + 1024, pwT + PACK_HEAD,
          tbo + b * 32, prevP, touts, zbuf, ld, praw, o);
      mlp_A<1, false><<<GG, 1024, 0, stream>>>(src, pwS, sb0 + b * 512,
          sbh + b * 1536, prevP, hg, o);
      mlp_B<1, true, false><<<GG, 1024, 0, stream>>>(src, hg,
          pwS + PACK_H + 2 * 262144, sbh + b * 1536 + 1024, pwS + PACK_HEAD,
          sbo + b * 32, prevP, touts, zbuf, ld, praw, o);
    }
    stats_kernel<<<1, 64, 0, stream>>>(praw, bn_lg + b * 64, bn_bt + b * 64,
                                       stats_param + (size_t)b * 128, ld_scalar);
  }

  final_kernel<<<(BROWS * 64) / 256, 256, 0, stream>>>(
      out, stats_param + 7 * 128, ld_scalar);
}